// Round 2
// 3147.282 us; speedup vs baseline: 1.8005x; 1.8005x over previous
//
#include <hip/hip_runtime.h>
#include <hip/hip_bf16.h>

#define N_NODES 10000
#define N_EDGES 320000
#define D_NODE 32
#define D_RAD 8
#define D_SPH 9
#define LAT 64
#define NHEAD 8
#define NL 2
#define GEN_W 280
#define WN_ENV 24

#define RS136 0.08574929257125442f   // 136^-0.5
#define RS8   0.35355339059327373f   // 8^-0.5

static_assert(N_EDGES % 4 == 0, "edge quads");

__device__ __forceinline__ int irrep_of(int d){ return (d==0)?0:((d<4)?1:2); }

__device__ __forceinline__ float wave_sum(float v){
  #pragma unroll
  for (int off=32; off; off>>=1) v += __shfl_xor(v, off);
  return v;
}

__device__ __forceinline__ void atomicMaxF(float* addr, float v){
  if (v >= 0.f) atomicMax((int*)addr, __float_as_int(v));
  else          atomicMin((unsigned int*)addr, __float_as_uint(v));
}

__device__ __forceinline__ float f4g(const float4& v, int i){
  return (i==0)?v.x:((i==1)?v.y:((i==2)?v.z:v.w));
}

__global__ void fill_neg_inf(float* p, int n){
  int i = blockIdx.x*blockDim.x + threadIdx.x;
  if (i < n) p[i] = __uint_as_float(0xff800000u);
}

// K1: pn = na@W_node, pc = na@W_center
__global__ void k_node_proj(const float* __restrict__ na,
                            const float* __restrict__ Wn,
                            const float* __restrict__ Wc,
                            float* __restrict__ pn, float* __restrict__ pc){
  int idx = blockIdx.x*blockDim.x + threadIdx.x;
  int n = idx >> 6, j = idx & 63;
  if (n >= N_NODES) return;
  float an = 0.f, ac = 0.f;
  #pragma unroll
  for (int k = 0; k < D_NODE; k++){
    float a = na[n*D_NODE + k];
    an += a * Wn[k*LAT + j];
    ac += a * Wc[k*LAT + j];
  }
  pn[idx] = an; pc[idx] = ac;
}

// K2: pe = pn[nb] * (phi@W_edge); m_node = segsum(pe)
__global__ void k_edge_msg(const float* __restrict__ phi,
                           const float* __restrict__ We,
                           const int* __restrict__ ec, const int* __restrict__ en,
                           const float* __restrict__ pn, float* __restrict__ mnode){
  int idx = blockIdx.x*blockDim.x + threadIdx.x;
  int e = idx >> 6, j = idx & 63;
  float d = 0.f;
  #pragma unroll
  for (int k = 0; k < D_RAD; k++) d += phi[e*D_RAD + k] * We[k*LAT + j];
  float pe = pn[en[e]*LAT + j] * d;
  atomicAdd(&mnode[ec[e]*LAT + j], pe);
}

// K3: h0 = h = LN([pc, m_node]@W_concat)
__global__ void k_node_h(const float* __restrict__ pc, const float* __restrict__ mnode,
                         const float* __restrict__ Wcat,
                         const float* __restrict__ g, const float* __restrict__ b,
                         float* __restrict__ h0, float* __restrict__ h){
  int n = blockIdx.x*(blockDim.x >> 6) + (threadIdx.x >> 6);
  int j = threadIdx.x & 63;
  if (n >= N_NODES) return;
  float acc = 0.f;
  for (int k = 0; k < LAT; k++) acc += pc[n*LAT + k] * Wcat[k*LAT + j];
  for (int k = 0; k < LAT; k++) acc += mnode[n*LAT + k] * Wcat[(LAT + k)*LAT + j];
  float mu = wave_sum(acc) * (1.f/64.f);
  float va = wave_sum(acc*acc) * (1.f/64.f) - mu*mu;
  float v = (acc - mu) * rsqrtf(va + 1e-5f) * g[j] + b[j];
  h0[n*LAT + j] = v; h[n*LAT + j] = v;
}

// K4a: T = LN(tcat@Wtcat). E=4 edges/wave; x-rows via wave-uniform float4 loads
// (scalar path), weights from LDS amortized over 4 edges. LDS 34.8KB -> 4 blk/CU.
__global__ void __launch_bounds__(256,4) k_tijA(
    const float* __restrict__ h0, const float* __restrict__ phi,
    const float* __restrict__ Wtcat,
    const float* __restrict__ lg, const float* __restrict__ lb,
    const int* __restrict__ ec, const int* __restrict__ en,
    float* __restrict__ T){
  __shared__ float swt[136*64];
  for (int i = threadIdx.x; i < 136*64; i += 256) swt[i] = Wtcat[i];
  __syncthreads();
  const int j = threadIdx.x & 63;
  const float gj = lg[j], bj = lb[j];
  int wid = blockIdx.x*4 + (threadIdx.x >> 6);
  int nw  = gridDim.x*4;
  for (int p = wid; p < N_EDGES/4; p += nw){
    const int eb = p*4;
    int4 cv = *(const int4*)(ec + eb);
    int4 nv = *(const int4*)(en + eb);
    int c0 = __builtin_amdgcn_readfirstlane(cv.x);
    int c1 = __builtin_amdgcn_readfirstlane(cv.y);
    int c2 = __builtin_amdgcn_readfirstlane(cv.z);
    int c3 = __builtin_amdgcn_readfirstlane(cv.w);
    int n0 = __builtin_amdgcn_readfirstlane(nv.x);
    int n1 = __builtin_amdgcn_readfirstlane(nv.y);
    int n2 = __builtin_amdgcn_readfirstlane(nv.z);
    int n3 = __builtin_amdgcn_readfirstlane(nv.w);
    const float4* hc0 = (const float4*)(h0 + (long)c0*LAT);
    const float4* hc1 = (const float4*)(h0 + (long)c1*LAT);
    const float4* hc2 = (const float4*)(h0 + (long)c2*LAT);
    const float4* hc3 = (const float4*)(h0 + (long)c3*LAT);
    const float4* hn0 = (const float4*)(h0 + (long)n0*LAT);
    const float4* hn1 = (const float4*)(h0 + (long)n1*LAT);
    const float4* hn2 = (const float4*)(h0 + (long)n2*LAT);
    const float4* hn3 = (const float4*)(h0 + (long)n3*LAT);
    float a0=0.f, a1=0.f, a2=0.f, a3=0.f;
    #pragma unroll 2
    for (int kk = 0; kk < 16; kk++){
      float4 xc0 = hc0[kk], xc1 = hc1[kk], xc2 = hc2[kk], xc3 = hc3[kk];
      float4 xn0 = hn0[kk], xn1 = hn1[kk], xn2 = hn2[kk], xn3 = hn3[kk];
      const float* w1 = swt + (kk*4)*64 + j;
      const float* w2 = swt + (64 + kk*4)*64 + j;
      #pragma unroll
      for (int i = 0; i < 4; i++){
        float u = w1[i*64], v = w2[i*64];
        a0 += f4g(xc0,i)*u + f4g(xn0,i)*v;
        a1 += f4g(xc1,i)*u + f4g(xn1,i)*v;
        a2 += f4g(xc2,i)*u + f4g(xn2,i)*v;
        a3 += f4g(xc3,i)*u + f4g(xn3,i)*v;
      }
    }
    const float4* ph = (const float4*)(phi + (long)eb*D_RAD);
    #pragma unroll
    for (int kk = 0; kk < 2; kk++){
      float4 p0 = ph[kk], p1 = ph[2+kk], p2 = ph[4+kk], p3 = ph[6+kk];
      const float* w = swt + (128 + kk*4)*64 + j;
      #pragma unroll
      for (int i = 0; i < 4; i++){
        float u = w[i*64];
        a0 += f4g(p0,i)*u; a1 += f4g(p1,i)*u; a2 += f4g(p2,i)*u; a3 += f4g(p3,i)*u;
      }
    }
    float accs[4] = {a0,a1,a2,a3};
    #pragma unroll
    for (int x = 0; x < 4; x++){
      float acc = accs[x] * RS136;
      float mu = wave_sum(acc) * (1.f/64.f);
      float va = wave_sum(acc*acc) * (1.f/64.f) - mu*mu;
      T[(long)(eb+x)*LAT + j] = (acc - mu) * rsqrtf(va + 1e-5f) * gj + bj;
    }
  }
}

// K4b: edge_out = t@Wtij/8; w0 = (t@Wt0)*(hj@Wh0)/64 scatter into Xacc.
// E=4, uniform x loads; LDS 28KB.
__global__ void __launch_bounds__(256,4) k_tijB(
    const float* __restrict__ T, const float* __restrict__ h0,
    const float* __restrict__ sph,
    const float* __restrict__ Wtij, const float* __restrict__ Wt0,
    const float* __restrict__ Wh0,
    const int* __restrict__ ec, const int* __restrict__ en,
    float* __restrict__ Xacc, float* __restrict__ edge_out){
  __shared__ float swij[64*64];
  __shared__ float sw0[64*24], sh0[64*24];
  for (int i = threadIdx.x; i < 64*64; i += 256) swij[i] = Wtij[i];
  for (int i = threadIdx.x; i < 64*24; i += 256){ sw0[i] = Wt0[i]; sh0[i] = Wh0[i]; }
  __syncthreads();
  const int j = threadIdx.x & 63;
  const int jc = (j < WN_ENV) ? j : 0;
  int wid = blockIdx.x*4 + (threadIdx.x >> 6);
  int nw  = gridDim.x*4;
  for (int p = wid; p < N_EDGES/4; p += nw){
    const int eb = p*4;
    int4 cv = *(const int4*)(ec + eb);
    int4 nv = *(const int4*)(en + eb);
    int ccs[4], nns[4];
    ccs[0] = __builtin_amdgcn_readfirstlane(cv.x);
    ccs[1] = __builtin_amdgcn_readfirstlane(cv.y);
    ccs[2] = __builtin_amdgcn_readfirstlane(cv.z);
    ccs[3] = __builtin_amdgcn_readfirstlane(cv.w);
    nns[0] = __builtin_amdgcn_readfirstlane(nv.x);
    nns[1] = __builtin_amdgcn_readfirstlane(nv.y);
    nns[2] = __builtin_amdgcn_readfirstlane(nv.z);
    nns[3] = __builtin_amdgcn_readfirstlane(nv.w);
    const float4* tp0 = (const float4*)(T + (long)(eb+0)*LAT);
    const float4* tp1 = (const float4*)(T + (long)(eb+1)*LAT);
    const float4* tp2 = (const float4*)(T + (long)(eb+2)*LAT);
    const float4* tp3 = (const float4*)(T + (long)(eb+3)*LAT);
    const float4* hp0 = (const float4*)(h0 + (long)nns[0]*LAT);
    const float4* hp1 = (const float4*)(h0 + (long)nns[1]*LAT);
    const float4* hp2 = (const float4*)(h0 + (long)nns[2]*LAT);
    const float4* hp3 = (const float4*)(h0 + (long)nns[3]*LAT);
    float eo[4]={0,0,0,0}, av[4]={0,0,0,0}, bv[4]={0,0,0,0};
    #pragma unroll 2
    for (int kk = 0; kk < 16; kk++){
      float4 tv[4] = {tp0[kk], tp1[kk], tp2[kk], tp3[kk]};
      float4 hv[4] = {hp0[kk], hp1[kk], hp2[kk], hp3[kk]};
      const float* w1 = swij + (kk*4)*64 + j;
      const float* w2 = sw0  + (kk*4)*24 + jc;
      const float* w3 = sh0  + (kk*4)*24 + jc;
      #pragma unroll
      for (int i = 0; i < 4; i++){
        float u = w1[i*64], a = w2[i*24], b = w3[i*24];
        #pragma unroll
        for (int x = 0; x < 4; x++){
          float tx = f4g(tv[x], i), hx = f4g(hv[x], i);
          eo[x] += tx*u; av[x] += tx*a; bv[x] += hx*b;
        }
      }
    }
    float w0s[4];
    #pragma unroll
    for (int x = 0; x < 4; x++){
      edge_out[(long)(eb+x)*LAT + j] = eo[x] * 0.125f;
      w0s[x] = av[x]*bv[x]*(0.125f*0.125f);
    }
    #pragma unroll
    for (int x = 0; x < 4; x++){
      #pragma unroll
      for (int rep = 0; rep < 2; rep++){
        int tt = j + rep*64;
        int m = tt/9, d = tt - (tt/9)*9;
        int wi = (tt < 72) ? (irrep_of(d)*NHEAD + m) : 0;
        float wv = __shfl(w0s[x], wi);
        if (tt < 72){
          atomicAdd(&Xacc[ccs[x]*72 + tt], sph[(long)(eb+x)*D_SPH + d] * wv);
        }
      }
    }
  }
}

// K5: X = so3_norm(Xacc)
__global__ void k_node_X0(const float* __restrict__ Xacc, float* __restrict__ X){
  int n = blockIdx.x*(blockDim.x >> 6) + (threadIdx.x >> 6);
  int j = threadIdx.x & 63;
  if (n >= N_NODES) return;
  float x0 = Xacc[n*72 + j];
  float x1 = (j < 8) ? Xacc[n*72 + 64 + j] : 0.f;
  float s0 = 0.f, s1 = 0.f, s2 = 0.f;
  { int d = j % 9; int k3 = irrep_of(d);
    if (k3 == 0) s0 = x0*x0; else if (k3 == 1) s1 = x0*x0; else s2 = x0*x0; }
  if (j < 8){ int d = (64 + j) % 9; int k3 = irrep_of(d);
    if (k3 == 0) s0 += x1*x1; else if (k3 == 1) s1 += x1*x1; else s2 += x1*x1; }
  s0 = wave_sum(s0); s1 = wave_sum(s1); s2 = wave_sum(s2);
  float sa = rsqrtf(s0*0.125f + 1e-5f), sb = rsqrtf(s1*0.125f + 1e-5f), sc = rsqrtf(s2*0.125f + 1e-5f);
  { int d = j % 9; int k3 = irrep_of(d);
    X[n*72 + j] = x0 * (k3==0 ? sa : (k3==1 ? sb : sc)); }
  if (j < 8){ int d = (64 + j) % 9; int k3 = irrep_of(d);
    X[n*72 + 64 + j] = x1 * (k3==0 ? sa : (k3==1 ? sb : sc)); }
}

// K6: attention logits + running max. E=4, uniform x loads.
__global__ void __launch_bounds__(256) k_att(const float* __restrict__ T, const float* __restrict__ h,
                     const float* __restrict__ Wq, const float* __restrict__ Wk,
                     const int* __restrict__ ec, const int* __restrict__ en,
                     float* __restrict__ att, float* __restrict__ attmax){
  __shared__ float sq[64*128], sk[64*128];
  for (int i = threadIdx.x; i < 64*128; i += 256){ sq[i] = Wq[i]; sk[i] = Wk[i]; }
  __syncthreads();
  const int j = threadIdx.x & 63;
  int wid = blockIdx.x*4 + (threadIdx.x >> 6);
  int nw  = gridDim.x*4;
  for (int p = wid; p < N_EDGES/4; p += nw){
    const int eb = p*4;
    int4 cv = *(const int4*)(ec + eb);
    int4 nv = *(const int4*)(en + eb);
    int ccs[4], nns[4];
    ccs[0] = __builtin_amdgcn_readfirstlane(cv.x);
    ccs[1] = __builtin_amdgcn_readfirstlane(cv.y);
    ccs[2] = __builtin_amdgcn_readfirstlane(cv.z);
    ccs[3] = __builtin_amdgcn_readfirstlane(cv.w);
    nns[0] = __builtin_amdgcn_readfirstlane(nv.x);
    nns[1] = __builtin_amdgcn_readfirstlane(nv.y);
    nns[2] = __builtin_amdgcn_readfirstlane(nv.z);
    nns[3] = __builtin_amdgcn_readfirstlane(nv.w);
    const float4* tp0 = (const float4*)(T + (long)(eb+0)*LAT);
    const float4* tp1 = (const float4*)(T + (long)(eb+1)*LAT);
    const float4* tp2 = (const float4*)(T + (long)(eb+2)*LAT);
    const float4* tp3 = (const float4*)(T + (long)(eb+3)*LAT);
    const float4* hp0 = (const float4*)(h + (long)nns[0]*LAT);
    const float4* hp1 = (const float4*)(h + (long)nns[1]*LAT);
    const float4* hp2 = (const float4*)(h + (long)nns[2]*LAT);
    const float4* hp3 = (const float4*)(h + (long)nns[3]*LAT);
    float qa[4]={0,0,0,0}, qb[4]={0,0,0,0}, ka[4]={0,0,0,0}, kb[4]={0,0,0,0};
    #pragma unroll 2
    for (int kk = 0; kk < 16; kk++){
      float4 tv[4] = {tp0[kk], tp1[kk], tp2[kk], tp3[kk]};
      float4 hv[4] = {hp0[kk], hp1[kk], hp2[kk], hp3[kk]};
      const float* wq = sq + (kk*4)*128 + j;
      const float* wk = sk + (kk*4)*128 + j;
      #pragma unroll
      for (int i = 0; i < 4; i++){
        float q0 = wq[i*128], q1 = wq[i*128 + 64];
        float k0 = wk[i*128], k1 = wk[i*128 + 64];
        #pragma unroll
        for (int x = 0; x < 4; x++){
          float tx = f4g(tv[x], i), hx = f4g(hv[x], i);
          qa[x] += tx*q0; qb[x] += tx*q1;
          ka[x] += hx*k0; kb[x] += hx*k1;
        }
      }
    }
    float pa[4], pb[4];
    #pragma unroll
    for (int x = 0; x < 4; x++){ pa[x] = qa[x]*ka[x]; pb[x] = qb[x]*kb[x]; }
    #pragma unroll
    for (int off = 8; off; off >>= 1){
      #pragma unroll
      for (int x = 0; x < 4; x++){
        pa[x] += __shfl_xor(pa[x], off);
        pb[x] += __shfl_xor(pb[x], off);
      }
    }
    if ((j & 15) == 0){
      int m = j >> 4;
      #pragma unroll
      for (int x = 0; x < 4; x++){
        float A = 4.f*pa[x], B = 4.f*pb[x];
        att[(long)(eb+x)*NHEAD + m] = A;
        att[(long)(eb+x)*NHEAD + 4 + m] = B;
        atomicMaxF(&attmax[ccs[x]*NHEAD + m], A);
        atomicMaxF(&attmax[ccs[x]*NHEAD + 4 + m], B);
      }
    }
  }
}

// K7a: env cols A = [0:64)+[88:120)+[152:184); hacc scatter; d_sph + d_eq(i<4);
// asum; Xacc part. E=4, uniform x loads, X rows read direct (L1).
__global__ void __launch_bounds__(256) k_envA(const float* __restrict__ T, const float* __restrict__ h,
                     const float* __restrict__ X,
                     const float* __restrict__ Wrs, const float* __restrict__ Whj,
                     const float* __restrict__ sph,
                     const float* __restrict__ att, const float* __restrict__ attmax,
                     const int* __restrict__ ec, const int* __restrict__ en,
                     float* __restrict__ hacc, float* __restrict__ asum,
                     float* __restrict__ Xacc){
  __shared__ float srs[64*128], shw[64*128];
  __shared__ float senv[4][4][128];
  for (int i = threadIdx.x; i < 64*128; i += 256){
    int k = i >> 7, s = i & 127;
    int c = s + (s < 64 ? 0 : (s < 96 ? 24 : 56));
    srs[i] = Wrs[k*GEN_W + c];
    shw[i] = Whj[k*GEN_W + c];
  }
  __syncthreads();
  const int j = threadIdx.x & 63, lw = threadIdx.x >> 6;
  int wid = blockIdx.x*4 + lw;
  int nw  = gridDim.x*4;
  for (int p = wid; p < N_EDGES/4; p += nw){
    const int eb = p*4;
    int4 cv = *(const int4*)(ec + eb);
    int4 nv = *(const int4*)(en + eb);
    int ccs[4], nns[4];
    ccs[0] = __builtin_amdgcn_readfirstlane(cv.x);
    ccs[1] = __builtin_amdgcn_readfirstlane(cv.y);
    ccs[2] = __builtin_amdgcn_readfirstlane(cv.z);
    ccs[3] = __builtin_amdgcn_readfirstlane(cv.w);
    nns[0] = __builtin_amdgcn_readfirstlane(nv.x);
    nns[1] = __builtin_amdgcn_readfirstlane(nv.y);
    nns[2] = __builtin_amdgcn_readfirstlane(nv.z);
    nns[3] = __builtin_amdgcn_readfirstlane(nv.w);
    const float4* tp0 = (const float4*)(T + (long)(eb+0)*LAT);
    const float4* tp1 = (const float4*)(T + (long)(eb+1)*LAT);
    const float4* tp2 = (const float4*)(T + (long)(eb+2)*LAT);
    const float4* tp3 = (const float4*)(T + (long)(eb+3)*LAT);
    const float4* hp0 = (const float4*)(h + (long)nns[0]*LAT);
    const float4* hp1 = (const float4*)(h + (long)nns[1]*LAT);
    const float4* hp2 = (const float4*)(h + (long)nns[2]*LAT);
    const float4* hp3 = (const float4*)(h + (long)nns[3]*LAT);
    float rA[4]={0,0,0,0}, rB[4]={0,0,0,0}, wA[4]={0,0,0,0}, wB[4]={0,0,0,0};
    #pragma unroll 2
    for (int kk = 0; kk < 16; kk++){
      float4 tv[4] = {tp0[kk], tp1[kk], tp2[kk], tp3[kk]};
      float4 hv[4] = {hp0[kk], hp1[kk], hp2[kk], hp3[kk]};
      const float* wr = srs + (kk*4)*128 + j;
      const float* wh = shw + (kk*4)*128 + j;
      #pragma unroll
      for (int i = 0; i < 4; i++){
        float r0 = wr[i*128], r1 = wr[i*128 + 64];
        float q0 = wh[i*128], q1 = wh[i*128 + 64];
        #pragma unroll
        for (int x = 0; x < 4; x++){
          float tx = f4g(tv[x], i), hx = f4g(hv[x], i);
          rA[x] += tx*r0; rB[x] += tx*r1;
          wA[x] += hx*q0; wB[x] += hx*q1;
        }
      }
    }
    #pragma unroll
    for (int x = 0; x < 4; x++){
      float eA = rA[x]*wA[x]*0.125f, eB = rB[x]*wB[x]*0.125f;
      atomicAdd(&hacc[ccs[x]*LAT + j], eA);
      senv[lw][x][j] = eA; senv[lw][x][64 + j] = eB;
    }
    __threadfence_block();
    if (j < 32){
      int x = j >> 3, m = j & 7;
      float ev = __expf(att[(long)(eb+x)*NHEAD + m] - attmax[ccs[x]*NHEAD + m]);
      atomicAdd(&asum[ccs[x]*NHEAD + m], ev);
    }
    #pragma unroll
    for (int x = 0; x < 4; x++){
      const long e = eb + x;
      const int cc = ccs[x];
      const float* Xr = X + (long)nns[x]*72;
      #pragma unroll
      for (int rep = 0; rep < 2; rep++){
        int tt = j + rep*64;
        if (tt < 72){
          int m = tt/9, d = tt - m*9, k3 = irrep_of(d);
          float ds = sph[e*D_SPH + d] * senv[lw][x][k3*8 + m];
          int sb = (k3==0) ? 24 : ((k3==1) ? 64 : 96);
          float dq = 0.f;
          #pragma unroll
          for (int i = 0; i < 4; i++) dq += Xr[i*9 + d] * senv[lw][x][sb + i*8 + m];
          float ev = __expf(att[e*NHEAD + m] - attmax[cc*NHEAD + m]);
          atomicAdd(&Xacc[cc*72 + tt], (ds + dq*RS8) * ev);
        }
      }
    }
    __threadfence_block();
  }
}

// K7b: env cols B = [56:88)+[120:152)+[184:216) -> d_eq(i>=4). E=4.
__global__ void __launch_bounds__(256) k_envB(const float* __restrict__ T, const float* __restrict__ h,
                     const float* __restrict__ X,
                     const float* __restrict__ Wrs, const float* __restrict__ Whj,
                     const float* __restrict__ att, const float* __restrict__ attmax,
                     const int* __restrict__ ec, const int* __restrict__ en,
                     float* __restrict__ Xacc){
  __shared__ float srs[64*96], shw[64*96];
  __shared__ float senv[4][4][96];
  for (int i = threadIdx.x; i < 64*96; i += 256){
    int k = i / 96, s = i - k*96;
    int c = s + (s < 32 ? 56 : (s < 64 ? 88 : 120));
    srs[i] = Wrs[k*GEN_W + c];
    shw[i] = Whj[k*GEN_W + c];
  }
  __syncthreads();
  const int j = threadIdx.x & 63, lw = threadIdx.x >> 6;
  int wid = blockIdx.x*4 + lw;
  int nw  = gridDim.x*4;
  for (int p = wid; p < N_EDGES/4; p += nw){
    const int eb = p*4;
    int4 cv = *(const int4*)(ec + eb);
    int4 nv = *(const int4*)(en + eb);
    int ccs[4], nns[4];
    ccs[0] = __builtin_amdgcn_readfirstlane(cv.x);
    ccs[1] = __builtin_amdgcn_readfirstlane(cv.y);
    ccs[2] = __builtin_amdgcn_readfirstlane(cv.z);
    ccs[3] = __builtin_amdgcn_readfirstlane(cv.w);
    nns[0] = __builtin_amdgcn_readfirstlane(nv.x);
    nns[1] = __builtin_amdgcn_readfirstlane(nv.y);
    nns[2] = __builtin_amdgcn_readfirstlane(nv.z);
    nns[3] = __builtin_amdgcn_readfirstlane(nv.w);
    const float4* tp0 = (const float4*)(T + (long)(eb+0)*LAT);
    const float4* tp1 = (const float4*)(T + (long)(eb+1)*LAT);
    const float4* tp2 = (const float4*)(T + (long)(eb+2)*LAT);
    const float4* tp3 = (const float4*)(T + (long)(eb+3)*LAT);
    const float4* hp0 = (const float4*)(h + (long)nns[0]*LAT);
    const float4* hp1 = (const float4*)(h + (long)nns[1]*LAT);
    const float4* hp2 = (const float4*)(h + (long)nns[2]*LAT);
    const float4* hp3 = (const float4*)(h + (long)nns[3]*LAT);
    float rA[4]={0,0,0,0}, rB[4]={0,0,0,0}, wA[4]={0,0,0,0}, wB[4]={0,0,0,0};
    #pragma unroll 2
    for (int kk = 0; kk < 16; kk++){
      float4 tv[4] = {tp0[kk], tp1[kk], tp2[kk], tp3[kk]};
      float4 hv[4] = {hp0[kk], hp1[kk], hp2[kk], hp3[kk]};
      #pragma unroll
      for (int i = 0; i < 4; i++){
        int k = kk*4 + i;
        float r0 = srs[k*96 + j];
        float q0 = shw[k*96 + j];
        float r1 = (j < 32) ? srs[k*96 + 64 + j] : 0.f;
        float q1 = (j < 32) ? shw[k*96 + 64 + j] : 0.f;
        #pragma unroll
        for (int x = 0; x < 4; x++){
          float tx = f4g(tv[x], i), hx = f4g(hv[x], i);
          rA[x] += tx*r0; rB[x] += tx*r1;
          wA[x] += hx*q0; wB[x] += hx*q1;
        }
      }
    }
    #pragma unroll
    for (int x = 0; x < 4; x++){
      senv[lw][x][j] = rA[x]*wA[x]*0.125f;
      if (j < 32) senv[lw][x][64 + j] = rB[x]*wB[x]*0.125f;
    }
    __threadfence_block();
    #pragma unroll
    for (int x = 0; x < 4; x++){
      const long e = eb + x;
      const int cc = ccs[x];
      const float* Xr = X + (long)nns[x]*72;
      #pragma unroll
      for (int rep = 0; rep < 2; rep++){
        int tt = j + rep*64;
        if (tt < 72){
          int m = tt/9, d = tt - m*9, k3 = irrep_of(d);
          int sb = (k3==0) ? 0 : ((k3==1) ? 32 : 64);
          float dq = 0.f;
          #pragma unroll
          for (int i = 0; i < 4; i++) dq += Xr[(i+4)*9 + d] * senv[lw][x][sb + i*8 + m];
          float ev = __expf(att[e*NHEAD + m] - attmax[cc*NHEAD + m]);
          atomicAdd(&Xacc[cc*72 + tt], dq*RS8*ev);
        }
      }
    }
    __threadfence_block();
  }
}

// K8: h = LN(h+hacc); X = so3_norm(X + Xacc/(attsum+1e-12))
__global__ void k_node_upd(const float* __restrict__ hacc, const float* __restrict__ attsum,
                           const float* __restrict__ Xacc,
                           const float* __restrict__ lg, const float* __restrict__ lb,
                           float* __restrict__ h, float* __restrict__ X){
  int n = blockIdx.x*(blockDim.x >> 6) + (threadIdx.x >> 6);
  int j = threadIdx.x & 63;
  if (n >= N_NODES) return;
  float hv = h[n*LAT + j] + hacc[n*LAT + j];
  float mu = wave_sum(hv) * (1.f/64.f);
  float va = wave_sum(hv*hv) * (1.f/64.f) - mu*mu;
  h[n*LAT + j] = (hv - mu) * rsqrtf(va + 1e-5f) * lg[j] + lb[j];

  float x0, x1 = 0.f;
  float s0 = 0.f, s1 = 0.f, s2 = 0.f;
  { int m = j/9, d = j - m*9;
    x0 = X[n*72 + j] + Xacc[n*72 + j] / (attsum[n*NHEAD + m] + 1e-12f);
    int k3 = irrep_of(d);
    if (k3 == 0) s0 = x0*x0; else if (k3 == 1) s1 = x0*x0; else s2 = x0*x0; }
  if (j < 8){ int tt = 64 + j; int m = tt/9, d = tt - m*9;
    x1 = X[n*72 + tt] + Xacc[n*72 + tt] / (attsum[n*NHEAD + m] + 1e-12f);
    int k3 = irrep_of(d);
    if (k3 == 0) s0 += x1*x1; else if (k3 == 1) s1 += x1*x1; else s2 += x1*x1; }
  s0 = wave_sum(s0); s1 = wave_sum(s1); s2 = wave_sum(s2);
  float sa = rsqrtf(s0*0.125f + 1e-5f), sb = rsqrtf(s1*0.125f + 1e-5f), sc = rsqrtf(s2*0.125f + 1e-5f);
  { int d = j % 9; int k3 = irrep_of(d);
    X[n*72 + j] = x0 * (k3==0 ? sa : (k3==1 ? sb : sc)); }
  if (j < 8){ int d = (64 + j) % 9; int k3 = irrep_of(d);
    X[n*72 + 64 + j] = x1 * (k3==0 ? sa : (k3==1 ? sb : sc)); }
}

// K9: w = h@W_hemb/8 -> (3,8,64); Xo = eq_linear(X,w); node_out
__global__ void k_node_out(const float* __restrict__ h, const float* __restrict__ X,
                           const float* __restrict__ Whemb,
                           float* __restrict__ out){
  __shared__ float sx[4][72];
  int n = blockIdx.x*(blockDim.x >> 6) + (threadIdx.x >> 6);
  int j = threadIdx.x & 63;
  int lw = threadIdx.x >> 6;
  if (n >= N_NODES) return;
  float hv = h[n*LAT + j];
  float wv[24];
  #pragma unroll
  for (int i = 0; i < 24; i++) wv[i] = 0.f;
  #pragma unroll 4
  for (int c = 0; c < LAT; c++){
    float hc = __shfl(hv, c);
    #pragma unroll
    for (int ki = 0; ki < 24; ki++)
      wv[ki] += hc * Whemb[c*1536 + ki*64 + j];
  }
  sx[lw][j] = X[n*72 + j];
  if (j < 8) sx[lw][64 + j] = X[n*72 + 64 + j];
  __threadfence_block();
  #pragma unroll
  for (int d = 0; d < 9; d++){
    int k3 = irrep_of(d);
    float acc = 0.f;
    #pragma unroll
    for (int i = 0; i < 8; i++) acc += sx[lw][i*9 + d] * wv[k3*8 + i];
    acc *= 0.125f * RS8;
    int pos;
    if (d == 0)      pos = n*576 + j;
    else if (d < 4)  pos = n*576 + 64  + j*3 + (d - 1);
    else             pos = n*576 + 256 + j*5 + (d - 4);
    out[pos] = acc;
  }
}

// ---- workspace layout (floats) — total 26.56M floats = 106.2 MB ----
static const long O_T    = 0;          // 20.48M  (E*64)
static const long O_ATT  = 20480000;   // 2.56M   (E*8) ; prologue pn/pc/mn alias here
static const long O_H0   = 23040000;   // 640k
static const long O_H    = 23680000;   // 640k
static const long O_X    = 24320000;   // 720k
static const long O_XACC = 25040000;   // 720k
static const long O_HACC = 25760000;   // 640k
static const long O_AMAX = 26400000;   // 80k
static const long O_ASUM = 26480000;   // 80k

extern "C" void kernel_launch(void* const* d_in, const int* in_sizes, int n_in,
                              void* d_out, int out_size, void* d_ws, size_t ws_size,
                              hipStream_t stream) {
  const float* na    = (const float*)d_in[0];
  const float* phi   = (const float*)d_in[1];
  const float* sph   = (const float*)d_in[2];
  const float* Wn    = (const float*)d_in[4];
  const float* Wc    = (const float*)d_in[5];
  const float* Wcat  = (const float*)d_in[6];
  const float* We    = (const float*)d_in[7];
  const float* ln0g  = (const float*)d_in[8];
  const float* ln0b  = (const float*)d_in[9];
  const float* lneg  = (const float*)d_in[10];
  const float* lneb  = (const float*)d_in[11];
  const float* Wtcat = (const float*)d_in[12];
  const float* Wt0   = (const float*)d_in[13];
  const float* Wh0   = (const float*)d_in[14];
  const float* Wrs   = (const float*)d_in[15];
  const float* Whj   = (const float*)d_in[16];
  const float* lnlg  = (const float*)d_in[17];
  const float* lnlb  = (const float*)d_in[18];
  const float* Wq    = (const float*)d_in[19];
  const float* Wk    = (const float*)d_in[20];
  const float* Whemb = (const float*)d_in[21];
  const float* Wtij  = (const float*)d_in[22];
  const int* ec = (const int*)d_in[23];
  const int* en = (const int*)d_in[24];

  float* ws   = (float*)d_ws;
  float* T    = ws + O_T;
  float* att  = ws + O_ATT;
  float* h0   = ws + O_H0;
  float* h    = ws + O_H;
  float* X    = ws + O_X;
  float* Xacc = ws + O_XACC;
  float* hacc = ws + O_HACC;
  float* amax = ws + O_AMAX;
  float* asum = ws + O_ASUM;
  // prologue-only buffers alias the att region (dead before k_att runs)
  float* pn   = att;
  float* pc   = att + 640000;
  float* mn   = att + 1280000;

  float* out      = (float*)d_out;
  float* edge_out = out + (long)N_NODES*576;

  hipMemsetAsync(mn,   0, 640000*sizeof(float), stream);
  hipMemsetAsync(Xacc, 0, 720000*sizeof(float), stream);

  k_node_proj<<<(N_NODES*64)/256, 256, 0, stream>>>(na, Wn, Wc, pn, pc);
  k_edge_msg<<<(N_EDGES*64)/256, 256, 0, stream>>>(phi, We, ec, en, pn, mn);
  k_node_h<<<N_NODES/4, 256, 0, stream>>>(pc, mn, Wcat, ln0g, ln0b, h0, h);
  k_tijA<<<1024, 256, 0, stream>>>(h0, phi, Wtcat, lneg, lneb, ec, en, T);
  k_tijB<<<1024, 256, 0, stream>>>(T, h0, sph, Wtij, Wt0, Wh0, ec, en, Xacc, edge_out);
  k_node_X0<<<N_NODES/4, 256, 0, stream>>>(Xacc, X);

  for (int l = 0; l < NL; l++){
    hipMemsetAsync(hacc, 0, 640000*sizeof(float), stream);
    hipMemsetAsync(Xacc, 0, 720000*sizeof(float), stream);
    hipMemsetAsync(asum, 0, 80000*sizeof(float), stream);
    fill_neg_inf<<<(80000 + 255)/256, 256, 0, stream>>>(amax, 80000);

    k_att<<<512, 256, 0, stream>>>(T, h, Wq + l*64*128, Wk + l*64*128, ec, en, att, amax);
    k_envA<<<512, 256, 0, stream>>>(T, h, X, Wrs + l*64*GEN_W, Whj + l*64*GEN_W, sph,
                                    att, amax, ec, en, hacc, asum, Xacc);
    k_envB<<<512, 256, 0, stream>>>(T, h, X, Wrs + l*64*GEN_W, Whj + l*64*GEN_W,
                                    att, amax, ec, en, Xacc);
    k_node_upd<<<N_NODES/4, 256, 0, stream>>>(hacc, asum, Xacc, lnlg + l*64, lnlb + l*64, h, X);
  }

  k_node_out<<<N_NODES/4, 256, 0, stream>>>(h, X, Whemb, out);
}

// Round 3
// 2500.754 us; speedup vs baseline: 2.2660x; 1.2585x over previous
//
#include <hip/hip_runtime.h>
#include <hip/hip_bf16.h>

#define N_NODES 10000
#define N_EDGES 320000
#define D_NODE 32
#define D_RAD 8
#define D_SPH 9
#define LAT 64
#define NHEAD 8
#define NL 2
#define GEN_W 280
#define WN_ENV 24

#define RS136 0.08574929257125442f   // 136^-0.5
#define RS8   0.35355339059327373f   // 8^-0.5

static_assert(N_EDGES % 4 == 0, "edge quads");

__device__ __forceinline__ int irrep_of(int d){ return (d==0)?0:((d<4)?1:2); }

__device__ __forceinline__ float wave_sum(float v){
  #pragma unroll
  for (int off=32; off; off>>=1) v += __shfl_xor(v, off);
  return v;
}

__device__ __forceinline__ void atomicMaxF(float* addr, float v){
  if (v >= 0.f) atomicMax((int*)addr, __float_as_int(v));
  else          atomicMin((unsigned int*)addr, __float_as_uint(v));
}

__device__ __forceinline__ float f4g(const float4& v, int i){
  return (i==0)?v.x:((i==1)?v.y:((i==2)?v.z:v.w));
}

__global__ void fill_neg_inf(float* p, int n){
  int i = blockIdx.x*blockDim.x + threadIdx.x;
  if (i < n) p[i] = __uint_as_float(0xff800000u);
}

// K1: pn = na@W_node, pc = na@W_center
__global__ void k_node_proj(const float* __restrict__ na,
                            const float* __restrict__ Wn,
                            const float* __restrict__ Wc,
                            float* __restrict__ pn, float* __restrict__ pc){
  int idx = blockIdx.x*blockDim.x + threadIdx.x;
  int n = idx >> 6, j = idx & 63;
  if (n >= N_NODES) return;
  float an = 0.f, ac = 0.f;
  #pragma unroll
  for (int k = 0; k < D_NODE; k++){
    float a = na[n*D_NODE + k];
    an += a * Wn[k*LAT + j];
    ac += a * Wc[k*LAT + j];
  }
  pn[idx] = an; pc[idx] = ac;
}

// K2: pe = pn[nb] * (phi@W_edge); m_node = segsum(pe)
__global__ void k_edge_msg(const float* __restrict__ phi,
                           const float* __restrict__ We,
                           const int* __restrict__ ec, const int* __restrict__ en,
                           const float* __restrict__ pn, float* __restrict__ mnode){
  int idx = blockIdx.x*blockDim.x + threadIdx.x;
  int e = idx >> 6, j = idx & 63;
  float d = 0.f;
  #pragma unroll
  for (int k = 0; k < D_RAD; k++) d += phi[e*D_RAD + k] * We[k*LAT + j];
  float pe = pn[en[e]*LAT + j] * d;
  atomicAdd(&mnode[ec[e]*LAT + j], pe);
}

// K3: h0 = h = LN([pc, m_node]@W_concat)
__global__ void k_node_h(const float* __restrict__ pc, const float* __restrict__ mnode,
                         const float* __restrict__ Wcat,
                         const float* __restrict__ g, const float* __restrict__ b,
                         float* __restrict__ h0, float* __restrict__ h){
  int n = blockIdx.x*(blockDim.x >> 6) + (threadIdx.x >> 6);
  int j = threadIdx.x & 63;
  if (n >= N_NODES) return;
  float acc = 0.f;
  for (int k = 0; k < LAT; k++) acc += pc[n*LAT + k] * Wcat[k*LAT + j];
  for (int k = 0; k < LAT; k++) acc += mnode[n*LAT + k] * Wcat[(LAT + k)*LAT + j];
  float mu = wave_sum(acc) * (1.f/64.f);
  float va = wave_sum(acc*acc) * (1.f/64.f) - mu*mu;
  float v = (acc - mu) * rsqrtf(va + 1e-5f) * g[j] + b[j];
  h0[n*LAT + j] = v; h[n*LAT + j] = v;
}

// K4: fused tij. Phase 1: t = LN(tcat@Wtcat) -> T (global) + tst (LDS broadcast).
// Phase 2: edge_out = t@Wtij/8; w0 = (t@Wt0)*(hj@Wh0)/64 -> Xacc scatter.
// t never re-read from HBM. LDS 66 KB -> 2 blk/CU.
__global__ void __launch_bounds__(256,2) k_tij(
    const float* __restrict__ h0, const float* __restrict__ phi,
    const float* __restrict__ sph,
    const float* __restrict__ Wtcat,
    const float* __restrict__ lg, const float* __restrict__ lb,
    const float* __restrict__ Wtij, const float* __restrict__ Wt0,
    const float* __restrict__ Wh0,
    const int* __restrict__ ec, const int* __restrict__ en,
    float* __restrict__ T, float* __restrict__ Xacc,
    float* __restrict__ edge_out){
  __shared__ float swt[136*64];
  __shared__ float swij[64*64];
  __shared__ float sw0[64*24], sh0[64*24];
  __shared__ float tst[4][4][64];
  for (int i = threadIdx.x; i < 136*64; i += 256) swt[i] = Wtcat[i];
  for (int i = threadIdx.x; i < 64*64;  i += 256) swij[i] = Wtij[i];
  for (int i = threadIdx.x; i < 64*24;  i += 256){ sw0[i] = Wt0[i]; sh0[i] = Wh0[i]; }
  __syncthreads();
  const int j = threadIdx.x & 63, lw = threadIdx.x >> 6;
  const float gj = lg[j], bj = lb[j];
  const int jc = (j < WN_ENV) ? j : 0;
  int wid = blockIdx.x*4 + lw;
  int nw  = gridDim.x*4;
  for (int p = wid; p < N_EDGES/4; p += nw){
    const int eb = p*4;
    int4 cv = *(const int4*)(ec + eb);
    int4 nv = *(const int4*)(en + eb);
    int c0 = __builtin_amdgcn_readfirstlane(cv.x);
    int c1 = __builtin_amdgcn_readfirstlane(cv.y);
    int c2 = __builtin_amdgcn_readfirstlane(cv.z);
    int c3 = __builtin_amdgcn_readfirstlane(cv.w);
    int n0 = __builtin_amdgcn_readfirstlane(nv.x);
    int n1 = __builtin_amdgcn_readfirstlane(nv.y);
    int n2 = __builtin_amdgcn_readfirstlane(nv.z);
    int n3 = __builtin_amdgcn_readfirstlane(nv.w);
    const float4* hc0 = (const float4*)(h0 + (long)c0*LAT);
    const float4* hc1 = (const float4*)(h0 + (long)c1*LAT);
    const float4* hc2 = (const float4*)(h0 + (long)c2*LAT);
    const float4* hc3 = (const float4*)(h0 + (long)c3*LAT);
    const float4* hn0 = (const float4*)(h0 + (long)n0*LAT);
    const float4* hn1 = (const float4*)(h0 + (long)n1*LAT);
    const float4* hn2 = (const float4*)(h0 + (long)n2*LAT);
    const float4* hn3 = (const float4*)(h0 + (long)n3*LAT);
    // ---- phase 1: tcat GEMV + LN ----
    float a0=0.f, a1=0.f, a2=0.f, a3=0.f;
    #pragma unroll 2
    for (int kk = 0; kk < 16; kk++){
      float4 xc0 = hc0[kk], xc1 = hc1[kk], xc2 = hc2[kk], xc3 = hc3[kk];
      float4 xn0 = hn0[kk], xn1 = hn1[kk], xn2 = hn2[kk], xn3 = hn3[kk];
      const float* w1 = swt + (kk*4)*64 + j;
      const float* w2 = swt + (64 + kk*4)*64 + j;
      #pragma unroll
      for (int i = 0; i < 4; i++){
        float u = w1[i*64], v = w2[i*64];
        a0 += f4g(xc0,i)*u + f4g(xn0,i)*v;
        a1 += f4g(xc1,i)*u + f4g(xn1,i)*v;
        a2 += f4g(xc2,i)*u + f4g(xn2,i)*v;
        a3 += f4g(xc3,i)*u + f4g(xn3,i)*v;
      }
    }
    const float4* ph = (const float4*)(phi + (long)eb*D_RAD);
    #pragma unroll
    for (int kk = 0; kk < 2; kk++){
      float4 p0 = ph[kk], p1 = ph[2+kk], p2 = ph[4+kk], p3 = ph[6+kk];
      const float* w = swt + (128 + kk*4)*64 + j;
      #pragma unroll
      for (int i = 0; i < 4; i++){
        float u = w[i*64];
        a0 += f4g(p0,i)*u; a1 += f4g(p1,i)*u; a2 += f4g(p2,i)*u; a3 += f4g(p3,i)*u;
      }
    }
    float accs[4] = {a0,a1,a2,a3};
    #pragma unroll
    for (int x = 0; x < 4; x++){
      float acc = accs[x] * RS136;
      float mu = wave_sum(acc) * (1.f/64.f);
      float va = wave_sum(acc*acc) * (1.f/64.f) - mu*mu;
      float t = (acc - mu) * rsqrtf(va + 1e-5f) * gj + bj;
      T[(long)(eb+x)*LAT + j] = t;
      tst[lw][x][j] = t;
    }
    __threadfence_block();
    // ---- phase 2: edge_out + w0 scatter ----
    float eo[4]={0,0,0,0}, av[4]={0,0,0,0}, bv[4]={0,0,0,0};
    #pragma unroll 2
    for (int kk = 0; kk < 16; kk++){
      float4 tv[4];
      tv[0] = *(const float4*)&tst[lw][0][kk*4];
      tv[1] = *(const float4*)&tst[lw][1][kk*4];
      tv[2] = *(const float4*)&tst[lw][2][kk*4];
      tv[3] = *(const float4*)&tst[lw][3][kk*4];
      float4 hv[4] = {hn0[kk], hn1[kk], hn2[kk], hn3[kk]};
      const float* w1 = swij + (kk*4)*64 + j;
      const float* w2 = sw0  + (kk*4)*24 + jc;
      const float* w3 = sh0  + (kk*4)*24 + jc;
      #pragma unroll
      for (int i = 0; i < 4; i++){
        float u = w1[i*64], a = w2[i*24], b = w3[i*24];
        #pragma unroll
        for (int x = 0; x < 4; x++){
          float tx = f4g(tv[x], i), hx = f4g(hv[x], i);
          eo[x] += tx*u; av[x] += tx*a; bv[x] += hx*b;
        }
      }
    }
    int ccs[4] = {c0, c1, c2, c3};
    float w0s[4];
    #pragma unroll
    for (int x = 0; x < 4; x++){
      edge_out[(long)(eb+x)*LAT + j] = eo[x] * 0.125f;
      w0s[x] = av[x]*bv[x]*(0.125f*0.125f);
    }
    #pragma unroll
    for (int x = 0; x < 4; x++){
      #pragma unroll
      for (int rep = 0; rep < 2; rep++){
        int tt = j + rep*64;
        int m = tt/9, d = tt - (tt/9)*9;
        int wi = (tt < 72) ? (irrep_of(d)*NHEAD + m) : 0;
        float wv = __shfl(w0s[x], wi);
        if (tt < 72){
          atomicAdd(&Xacc[ccs[x]*72 + tt], sph[(long)(eb+x)*D_SPH + d] * wv);
        }
      }
    }
    __threadfence_block();
  }
}

// K5: X = so3_norm(Xacc)
__global__ void k_node_X0(const float* __restrict__ Xacc, float* __restrict__ X){
  int n = blockIdx.x*(blockDim.x >> 6) + (threadIdx.x >> 6);
  int j = threadIdx.x & 63;
  if (n >= N_NODES) return;
  float x0 = Xacc[n*72 + j];
  float x1 = (j < 8) ? Xacc[n*72 + 64 + j] : 0.f;
  float s0 = 0.f, s1 = 0.f, s2 = 0.f;
  { int d = j % 9; int k3 = irrep_of(d);
    if (k3 == 0) s0 = x0*x0; else if (k3 == 1) s1 = x0*x0; else s2 = x0*x0; }
  if (j < 8){ int d = (64 + j) % 9; int k3 = irrep_of(d);
    if (k3 == 0) s0 += x1*x1; else if (k3 == 1) s1 += x1*x1; else s2 += x1*x1; }
  s0 = wave_sum(s0); s1 = wave_sum(s1); s2 = wave_sum(s2);
  float sa = rsqrtf(s0*0.125f + 1e-5f), sb = rsqrtf(s1*0.125f + 1e-5f), sc = rsqrtf(s2*0.125f + 1e-5f);
  { int d = j % 9; int k3 = irrep_of(d);
    X[n*72 + j] = x0 * (k3==0 ? sa : (k3==1 ? sb : sc)); }
  if (j < 8){ int d = (64 + j) % 9; int k3 = irrep_of(d);
    X[n*72 + 64 + j] = x1 * (k3==0 ? sa : (k3==1 ? sb : sc)); }
}

// K6: attention logits + running max. E=4, uniform x loads.
__global__ void __launch_bounds__(256) k_att(const float* __restrict__ T, const float* __restrict__ h,
                     const float* __restrict__ Wq, const float* __restrict__ Wk,
                     const int* __restrict__ ec, const int* __restrict__ en,
                     float* __restrict__ att, float* __restrict__ attmax){
  __shared__ float sq[64*128], sk[64*128];
  for (int i = threadIdx.x; i < 64*128; i += 256){ sq[i] = Wq[i]; sk[i] = Wk[i]; }
  __syncthreads();
  const int j = threadIdx.x & 63;
  int wid = blockIdx.x*4 + (threadIdx.x >> 6);
  int nw  = gridDim.x*4;
  for (int p = wid; p < N_EDGES/4; p += nw){
    const int eb = p*4;
    int4 cv = *(const int4*)(ec + eb);
    int4 nv = *(const int4*)(en + eb);
    int ccs[4], nns[4];
    ccs[0] = __builtin_amdgcn_readfirstlane(cv.x);
    ccs[1] = __builtin_amdgcn_readfirstlane(cv.y);
    ccs[2] = __builtin_amdgcn_readfirstlane(cv.z);
    ccs[3] = __builtin_amdgcn_readfirstlane(cv.w);
    nns[0] = __builtin_amdgcn_readfirstlane(nv.x);
    nns[1] = __builtin_amdgcn_readfirstlane(nv.y);
    nns[2] = __builtin_amdgcn_readfirstlane(nv.z);
    nns[3] = __builtin_amdgcn_readfirstlane(nv.w);
    const float4* tp0 = (const float4*)(T + (long)(eb+0)*LAT);
    const float4* tp1 = (const float4*)(T + (long)(eb+1)*LAT);
    const float4* tp2 = (const float4*)(T + (long)(eb+2)*LAT);
    const float4* tp3 = (const float4*)(T + (long)(eb+3)*LAT);
    const float4* hp0 = (const float4*)(h + (long)nns[0]*LAT);
    const float4* hp1 = (const float4*)(h + (long)nns[1]*LAT);
    const float4* hp2 = (const float4*)(h + (long)nns[2]*LAT);
    const float4* hp3 = (const float4*)(h + (long)nns[3]*LAT);
    float qa[4]={0,0,0,0}, qb[4]={0,0,0,0}, ka[4]={0,0,0,0}, kb[4]={0,0,0,0};
    #pragma unroll 2
    for (int kk = 0; kk < 16; kk++){
      float4 tv[4] = {tp0[kk], tp1[kk], tp2[kk], tp3[kk]};
      float4 hv[4] = {hp0[kk], hp1[kk], hp2[kk], hp3[kk]};
      const float* wq = sq + (kk*4)*128 + j;
      const float* wk = sk + (kk*4)*128 + j;
      #pragma unroll
      for (int i = 0; i < 4; i++){
        float q0 = wq[i*128], q1 = wq[i*128 + 64];
        float k0 = wk[i*128], k1 = wk[i*128 + 64];
        #pragma unroll
        for (int x = 0; x < 4; x++){
          float tx = f4g(tv[x], i), hx = f4g(hv[x], i);
          qa[x] += tx*q0; qb[x] += tx*q1;
          ka[x] += hx*k0; kb[x] += hx*k1;
        }
      }
    }
    float pa[4], pb[4];
    #pragma unroll
    for (int x = 0; x < 4; x++){ pa[x] = qa[x]*ka[x]; pb[x] = qb[x]*kb[x]; }
    #pragma unroll
    for (int off = 8; off; off >>= 1){
      #pragma unroll
      for (int x = 0; x < 4; x++){
        pa[x] += __shfl_xor(pa[x], off);
        pb[x] += __shfl_xor(pb[x], off);
      }
    }
    if ((j & 15) == 0){
      int m = j >> 4;
      #pragma unroll
      for (int x = 0; x < 4; x++){
        float A = 4.f*pa[x], B = 4.f*pb[x];
        att[(long)(eb+x)*NHEAD + m] = A;
        att[(long)(eb+x)*NHEAD + 4 + m] = B;
        atomicMaxF(&attmax[ccs[x]*NHEAD + m], A);
        atomicMaxF(&attmax[ccs[x]*NHEAD + 4 + m], B);
      }
    }
  }
}

// K7: merged env kernel — all 216 used cols of env in one pass.
// Weights in LDS as [k][j*4+g] so each lane does one ds_read_b128 per matrix
// per k. env staged per wave in senv; exp staged once per (edge,head) in sev.
// One atomicAdd per (edge,tt) into Xacc (was two). LDS 156 KB -> 1 blk (8 waves)/CU.
__global__ void __launch_bounds__(512,1) k_env(
    const float* __restrict__ T, const float* __restrict__ h,
    const float* __restrict__ X,
    const float* __restrict__ Wrs, const float* __restrict__ Whj,
    const float* __restrict__ sph,
    const float* __restrict__ att, const float* __restrict__ attmax,
    const int* __restrict__ ec, const int* __restrict__ en,
    float* __restrict__ hacc, float* __restrict__ asum,
    float* __restrict__ Xacc){
  __shared__ float srs[64*256], shw[64*256];
  __shared__ float senv[8][4][216];
  __shared__ float sev[8][32];
  for (int i = threadIdx.x; i < 64*256; i += 512){
    int k = i >> 8, r = i & 255;
    int col = (r & 3)*64 + (r >> 2);
    float a = 0.f, b = 0.f;
    if (col < 216){ a = Wrs[k*GEN_W + col]; b = Whj[k*GEN_W + col]; }
    srs[i] = a; shw[i] = b;
  }
  __syncthreads();
  const int j = threadIdx.x & 63, lw = threadIdx.x >> 6;
  int wid = blockIdx.x*8 + lw;
  int nw  = gridDim.x*8;
  for (int p = wid; p < N_EDGES/4; p += nw){
    const int eb = p*4;
    int4 cv = *(const int4*)(ec + eb);
    int4 nv = *(const int4*)(en + eb);
    int c0 = __builtin_amdgcn_readfirstlane(cv.x);
    int c1 = __builtin_amdgcn_readfirstlane(cv.y);
    int c2 = __builtin_amdgcn_readfirstlane(cv.z);
    int c3 = __builtin_amdgcn_readfirstlane(cv.w);
    int n0 = __builtin_amdgcn_readfirstlane(nv.x);
    int n1 = __builtin_amdgcn_readfirstlane(nv.y);
    int n2 = __builtin_amdgcn_readfirstlane(nv.z);
    int n3 = __builtin_amdgcn_readfirstlane(nv.w);
    const float4* tp0 = (const float4*)(T + (long)(eb+0)*LAT);
    const float4* tp1 = (const float4*)(T + (long)(eb+1)*LAT);
    const float4* tp2 = (const float4*)(T + (long)(eb+2)*LAT);
    const float4* tp3 = (const float4*)(T + (long)(eb+3)*LAT);
    const float4* hp0 = (const float4*)(h + (long)n0*LAT);
    const float4* hp1 = (const float4*)(h + (long)n1*LAT);
    const float4* hp2 = (const float4*)(h + (long)n2*LAT);
    const float4* hp3 = (const float4*)(h + (long)n3*LAT);
    float4 aT[4], aH[4];
    #pragma unroll
    for (int x = 0; x < 4; x++){
      aT[x] = make_float4(0.f,0.f,0.f,0.f);
      aH[x] = make_float4(0.f,0.f,0.f,0.f);
    }
    #pragma unroll 2
    for (int kk = 0; kk < 16; kk++){
      float4 tv[4] = {tp0[kk], tp1[kk], tp2[kk], tp3[kk]};
      float4 hv[4] = {hp0[kk], hp1[kk], hp2[kk], hp3[kk]};
      #pragma unroll
      for (int i = 0; i < 4; i++){
        int k = kk*4 + i;
        const float4 r4 = *(const float4*)(srs + k*256 + j*4);
        const float4 q4 = *(const float4*)(shw + k*256 + j*4);
        #pragma unroll
        for (int x = 0; x < 4; x++){
          float tx = f4g(tv[x], i), hx = f4g(hv[x], i);
          aT[x].x += tx*r4.x; aT[x].y += tx*r4.y; aT[x].z += tx*r4.z; aT[x].w += tx*r4.w;
          aH[x].x += hx*q4.x; aH[x].y += hx*q4.y; aH[x].z += hx*q4.z; aH[x].w += hx*q4.w;
        }
      }
    }
    int ccs[4] = {c0, c1, c2, c3};
    int nns[4] = {n0, n1, n2, n3};
    #pragma unroll
    for (int x = 0; x < 4; x++){
      float e0 = aT[x].x*aH[x].x*0.125f;
      float e1 = aT[x].y*aH[x].y*0.125f;
      float e2 = aT[x].z*aH[x].z*0.125f;
      float e3 = aT[x].w*aH[x].w*0.125f;
      atomicAdd(&hacc[ccs[x]*LAT + j], e0);
      senv[lw][x][j] = e0;
      senv[lw][x][64 + j] = e1;
      senv[lw][x][128 + j] = e2;
      if (j < 24) senv[lw][x][192 + j] = e3;
    }
    if (j < 32){
      int x = j >> 3, m = j & 7;
      int cc = (x==0)?c0:((x==1)?c1:((x==2)?c2:c3));
      float ev = __expf(att[(long)(eb+x)*NHEAD + m] - attmax[cc*NHEAD + m]);
      sev[lw][j] = ev;
      atomicAdd(&asum[cc*NHEAD + m], ev);
    }
    __threadfence_block();
    #pragma unroll
    for (int x = 0; x < 4; x++){
      const long e = eb + x;
      const int cc = ccs[x];
      const float* Xr = X + (long)nns[x]*72;
      #pragma unroll
      for (int rep = 0; rep < 2; rep++){
        int tt = j + rep*64;
        if (tt < 72){
          int m = tt/9, d = tt - m*9, k3 = irrep_of(d);
          float ds = sph[e*D_SPH + d] * senv[lw][x][k3*8 + m];
          float dq = 0.f;
          #pragma unroll
          for (int i = 0; i < 8; i++) dq += Xr[i*9 + d] * senv[lw][x][24 + k3*64 + i*8 + m];
          float val = (ds + dq*RS8) * sev[lw][x*8 + m];
          atomicAdd(&Xacc[cc*72 + tt], val);
        }
      }
    }
    __threadfence_block();
  }
}

// K8: h = LN(h+hacc); X = so3_norm(X + Xacc/(attsum+1e-12))
__global__ void k_node_upd(const float* __restrict__ hacc, const float* __restrict__ attsum,
                           const float* __restrict__ Xacc,
                           const float* __restrict__ lg, const float* __restrict__ lb,
                           float* __restrict__ h, float* __restrict__ X){
  int n = blockIdx.x*(blockDim.x >> 6) + (threadIdx.x >> 6);
  int j = threadIdx.x & 63;
  if (n >= N_NODES) return;
  float hv = h[n*LAT + j] + hacc[n*LAT + j];
  float mu = wave_sum(hv) * (1.f/64.f);
  float va = wave_sum(hv*hv) * (1.f/64.f) - mu*mu;
  h[n*LAT + j] = (hv - mu) * rsqrtf(va + 1e-5f) * lg[j] + lb[j];

  float x0, x1 = 0.f;
  float s0 = 0.f, s1 = 0.f, s2 = 0.f;
  { int m = j/9, d = j - m*9;
    x0 = X[n*72 + j] + Xacc[n*72 + j] / (attsum[n*NHEAD + m] + 1e-12f);
    int k3 = irrep_of(d);
    if (k3 == 0) s0 = x0*x0; else if (k3 == 1) s1 = x0*x0; else s2 = x0*x0; }
  if (j < 8){ int tt = 64 + j; int m = tt/9, d = tt - m*9;
    x1 = X[n*72 + tt] + Xacc[n*72 + tt] / (attsum[n*NHEAD + m] + 1e-12f);
    int k3 = irrep_of(d);
    if (k3 == 0) s0 += x1*x1; else if (k3 == 1) s1 += x1*x1; else s2 += x1*x1; }
  s0 = wave_sum(s0); s1 = wave_sum(s1); s2 = wave_sum(s2);
  float sa = rsqrtf(s0*0.125f + 1e-5f), sb = rsqrtf(s1*0.125f + 1e-5f), sc = rsqrtf(s2*0.125f + 1e-5f);
  { int d = j % 9; int k3 = irrep_of(d);
    X[n*72 + j] = x0 * (k3==0 ? sa : (k3==1 ? sb : sc)); }
  if (j < 8){ int d = (64 + j) % 9; int k3 = irrep_of(d);
    X[n*72 + 64 + j] = x1 * (k3==0 ? sa : (k3==1 ? sb : sc)); }
}

// K9: w = h@W_hemb/8 -> (3,8,64); Xo = eq_linear(X,w); node_out
__global__ void k_node_out(const float* __restrict__ h, const float* __restrict__ X,
                           const float* __restrict__ Whemb,
                           float* __restrict__ out){
  __shared__ float sx[4][72];
  int n = blockIdx.x*(blockDim.x >> 6) + (threadIdx.x >> 6);
  int j = threadIdx.x & 63;
  int lw = threadIdx.x >> 6;
  if (n >= N_NODES) return;
  float hv = h[n*LAT + j];
  float wv[24];
  #pragma unroll
  for (int i = 0; i < 24; i++) wv[i] = 0.f;
  #pragma unroll 4
  for (int c = 0; c < LAT; c++){
    float hc = __shfl(hv, c);
    #pragma unroll
    for (int ki = 0; ki < 24; ki++)
      wv[ki] += hc * Whemb[c*1536 + ki*64 + j];
  }
  sx[lw][j] = X[n*72 + j];
  if (j < 8) sx[lw][64 + j] = X[n*72 + 64 + j];
  __threadfence_block();
  #pragma unroll
  for (int d = 0; d < 9; d++){
    int k3 = irrep_of(d);
    float acc = 0.f;
    #pragma unroll
    for (int i = 0; i < 8; i++) acc += sx[lw][i*9 + d] * wv[k3*8 + i];
    acc *= 0.125f * RS8;
    int pos;
    if (d == 0)      pos = n*576 + j;
    else if (d < 4)  pos = n*576 + 64  + j*3 + (d - 1);
    else             pos = n*576 + 256 + j*5 + (d - 4);
    out[pos] = acc;
  }
}

// ---- workspace layout (floats) — total 26.56M floats = 106.2 MB ----
static const long O_T    = 0;          // 20.48M  (E*64)
static const long O_ATT  = 20480000;   // 2.56M   (E*8) ; prologue pn/pc/mn alias here
static const long O_H0   = 23040000;   // 640k
static const long O_H    = 23680000;   // 640k
static const long O_X    = 24320000;   // 720k
static const long O_XACC = 25040000;   // 720k
static const long O_HACC = 25760000;   // 640k
static const long O_AMAX = 26400000;   // 80k
static const long O_ASUM = 26480000;   // 80k

extern "C" void kernel_launch(void* const* d_in, const int* in_sizes, int n_in,
                              void* d_out, int out_size, void* d_ws, size_t ws_size,
                              hipStream_t stream) {
  const float* na    = (const float*)d_in[0];
  const float* phi   = (const float*)d_in[1];
  const float* sph   = (const float*)d_in[2];
  const float* Wn    = (const float*)d_in[4];
  const float* Wc    = (const float*)d_in[5];
  const float* Wcat  = (const float*)d_in[6];
  const float* We    = (const float*)d_in[7];
  const float* ln0g  = (const float*)d_in[8];
  const float* ln0b  = (const float*)d_in[9];
  const float* lneg  = (const float*)d_in[10];
  const float* lneb  = (const float*)d_in[11];
  const float* Wtcat = (const float*)d_in[12];
  const float* Wt0   = (const float*)d_in[13];
  const float* Wh0   = (const float*)d_in[14];
  const float* Wrs   = (const float*)d_in[15];
  const float* Whj   = (const float*)d_in[16];
  const float* lnlg  = (const float*)d_in[17];
  const float* lnlb  = (const float*)d_in[18];
  const float* Wq    = (const float*)d_in[19];
  const float* Wk    = (const float*)d_in[20];
  const float* Whemb = (const float*)d_in[21];
  const float* Wtij  = (const float*)d_in[22];
  const int* ec = (const int*)d_in[23];
  const int* en = (const int*)d_in[24];

  float* ws   = (float*)d_ws;
  float* T    = ws + O_T;
  float* att  = ws + O_ATT;
  float* h0   = ws + O_H0;
  float* h    = ws + O_H;
  float* X    = ws + O_X;
  float* Xacc = ws + O_XACC;
  float* hacc = ws + O_HACC;
  float* amax = ws + O_AMAX;
  float* asum = ws + O_ASUM;
  // prologue-only buffers alias the att region (dead before k_att runs)
  float* pn   = att;
  float* pc   = att + 640000;
  float* mn   = att + 1280000;

  float* out      = (float*)d_out;
  float* edge_out = out + (long)N_NODES*576;

  hipMemsetAsync(mn,   0, 640000*sizeof(float), stream);
  hipMemsetAsync(Xacc, 0, 720000*sizeof(float), stream);

  k_node_proj<<<(N_NODES*64)/256, 256, 0, stream>>>(na, Wn, Wc, pn, pc);
  k_edge_msg<<<(N_EDGES*64)/256, 256, 0, stream>>>(phi, We, ec, en, pn, mn);
  k_node_h<<<N_NODES/4, 256, 0, stream>>>(pc, mn, Wcat, ln0g, ln0b, h0, h);
  k_tij<<<512, 256, 0, stream>>>(h0, phi, sph, Wtcat, lneg, lneb, Wtij, Wt0, Wh0,
                                 ec, en, T, Xacc, edge_out);
  k_node_X0<<<N_NODES/4, 256, 0, stream>>>(Xacc, X);

  for (int l = 0; l < NL; l++){
    hipMemsetAsync(hacc, 0, 640000*sizeof(float), stream);
    hipMemsetAsync(Xacc, 0, 720000*sizeof(float), stream);
    hipMemsetAsync(asum, 0, 80000*sizeof(float), stream);
    fill_neg_inf<<<(80000 + 255)/256, 256, 0, stream>>>(amax, 80000);

    k_att<<<512, 256, 0, stream>>>(T, h, Wq + l*64*128, Wk + l*64*128, ec, en, att, amax);
    k_env<<<256, 512, 0, stream>>>(T, h, X, Wrs + l*64*GEN_W, Whj + l*64*GEN_W, sph,
                                   att, amax, ec, en, hacc, asum, Xacc);
    k_node_upd<<<N_NODES/4, 256, 0, stream>>>(hacc, asum, Xacc, lnlg + l*64, lnlb + l*64, h, X);
  }

  k_node_out<<<N_NODES/4, 256, 0, stream>>>(h, X, Whemb, out);
}

// Round 4
// 2136.419 us; speedup vs baseline: 2.6524x; 1.1705x over previous
//
#include <hip/hip_runtime.h>
#include <hip/hip_bf16.h>

#define N_NODES 10000
#define N_EDGES 320000
#define D_NODE 32
#define D_RAD 8
#define D_SPH 9
#define LAT 64
#define NHEAD 8
#define NL 2
#define GEN_W 280
#define WN_ENV 24

#define RS136 0.08574929257125442f   // 136^-0.5
#define RS8   0.35355339059327373f   // 8^-0.5

static_assert(N_EDGES % 4 == 0, "edge quads");

__device__ __forceinline__ int irrep_of(int d){ return (d==0)?0:((d<4)?1:2); }

__device__ __forceinline__ float wave_sum(float v){
  #pragma unroll
  for (int off=32; off; off>>=1) v += __shfl_xor(v, off);
  return v;
}

__device__ __forceinline__ void atomicMaxF(float* addr, float v){
  if (v >= 0.f) atomicMax((int*)addr, __float_as_int(v));
  else          atomicMin((unsigned int*)addr, __float_as_uint(v));
}

__device__ __forceinline__ float f4g(const float4& v, int i){
  return (i==0)?v.x:((i==1)?v.y:((i==2)?v.z:v.w));
}

__global__ void fill_neg_inf(float* p, int n){
  int i = blockIdx.x*blockDim.x + threadIdx.x;
  if (i < n) p[i] = __uint_as_float(0xff800000u);
}

// K1: pn = na@W_node, pc = na@W_center
__global__ void k_node_proj(const float* __restrict__ na,
                            const float* __restrict__ Wn,
                            const float* __restrict__ Wc,
                            float* __restrict__ pn, float* __restrict__ pc){
  int idx = blockIdx.x*blockDim.x + threadIdx.x;
  int n = idx >> 6, j = idx & 63;
  if (n >= N_NODES) return;
  float an = 0.f, ac = 0.f;
  #pragma unroll
  for (int k = 0; k < D_NODE; k++){
    float a = na[n*D_NODE + k];
    an += a * Wn[k*LAT + j];
    ac += a * Wc[k*LAT + j];
  }
  pn[idx] = an; pc[idx] = ac;
}

// K2: pe = pn[nb] * (phi@W_edge); m_node = segsum(pe). E=4, We in LDS.
__global__ void __launch_bounds__(256,4) k_edge_msg(const float* __restrict__ phi,
                           const float* __restrict__ We,
                           const int* __restrict__ ec, const int* __restrict__ en,
                           const float* __restrict__ pn, float* __restrict__ mnode){
  __shared__ float swe[8*64];
  for (int i = threadIdx.x; i < 8*64; i += 256) swe[i] = We[i];
  __syncthreads();
  const int j = threadIdx.x & 63;
  int wid = blockIdx.x*4 + (threadIdx.x >> 6);
  int nw  = gridDim.x*4;
  for (int p = wid; p < N_EDGES/4; p += nw){
    const int eb = p*4;
    int4 cv = *(const int4*)(ec + eb);
    int4 nv = *(const int4*)(en + eb);
    int c0 = __builtin_amdgcn_readfirstlane(cv.x);
    int c1 = __builtin_amdgcn_readfirstlane(cv.y);
    int c2 = __builtin_amdgcn_readfirstlane(cv.z);
    int c3 = __builtin_amdgcn_readfirstlane(cv.w);
    int n0 = __builtin_amdgcn_readfirstlane(nv.x);
    int n1 = __builtin_amdgcn_readfirstlane(nv.y);
    int n2 = __builtin_amdgcn_readfirstlane(nv.z);
    int n3 = __builtin_amdgcn_readfirstlane(nv.w);
    const float4* ph = (const float4*)(phi + (long)eb*D_RAD);
    float d0=0.f, d1=0.f, d2=0.f, d3=0.f;
    #pragma unroll
    for (int kk = 0; kk < 2; kk++){
      float4 p0=ph[kk], p1=ph[2+kk], p2=ph[4+kk], p3=ph[6+kk];
      #pragma unroll
      for (int i = 0; i < 4; i++){
        float u = swe[(kk*4+i)*64 + j];
        d0+=f4g(p0,i)*u; d1+=f4g(p1,i)*u; d2+=f4g(p2,i)*u; d3+=f4g(p3,i)*u;
      }
    }
    atomicAdd(&mnode[(long)c0*LAT + j], pn[(long)n0*LAT + j] * d0);
    atomicAdd(&mnode[(long)c1*LAT + j], pn[(long)n1*LAT + j] * d1);
    atomicAdd(&mnode[(long)c2*LAT + j], pn[(long)n2*LAT + j] * d2);
    atomicAdd(&mnode[(long)c3*LAT + j], pn[(long)n3*LAT + j] * d3);
  }
}

// K3: h0 = h = LN([pc, m_node]@W_concat)
__global__ void k_node_h(const float* __restrict__ pc, const float* __restrict__ mnode,
                         const float* __restrict__ Wcat,
                         const float* __restrict__ g, const float* __restrict__ b,
                         float* __restrict__ h0, float* __restrict__ h){
  int n = blockIdx.x*(blockDim.x >> 6) + (threadIdx.x >> 6);
  int j = threadIdx.x & 63;
  if (n >= N_NODES) return;
  float acc = 0.f;
  for (int k = 0; k < LAT; k++) acc += pc[n*LAT + k] * Wcat[k*LAT + j];
  for (int k = 0; k < LAT; k++) acc += mnode[n*LAT + k] * Wcat[(LAT + k)*LAT + j];
  float mu = wave_sum(acc) * (1.f/64.f);
  float va = wave_sum(acc*acc) * (1.f/64.f) - mu*mu;
  float v = (acc - mu) * rsqrtf(va + 1e-5f) * g[j] + b[j];
  h0[n*LAT + j] = v; h[n*LAT + j] = v;
}

// K3b: P0[n] = [ h0@Wtcat[0:64]*RS136 | h0@Wtcat[64:128]*RS136 | h0@Wh0*0.125 ]
__global__ void __launch_bounds__(256) k_pre0(const float* __restrict__ h0,
                       const float* __restrict__ Wtcat, const float* __restrict__ Wh0,
                       float* __restrict__ P0){
  __shared__ float sw[64*152];
  for (int i = threadIdx.x; i < 64*152; i += 256){
    int k = i / 152, c = i - k*152;
    float v;
    if (c < 64)       v = Wtcat[k*64 + c] * RS136;
    else if (c < 128) v = Wtcat[(64 + k)*64 + (c - 64)] * RS136;
    else              v = Wh0[k*24 + (c - 128)] * 0.125f;
    sw[i] = v;
  }
  __syncthreads();
  const int j = threadIdx.x & 63;
  int wid = blockIdx.x*4 + (threadIdx.x >> 6);
  int nw = gridDim.x*4;
  for (int n = wid; n < N_NODES; n += nw){
    const float4* xp = (const float4*)(h0 + (long)n*LAT);
    float a0=0.f, a1=0.f, a2=0.f;
    #pragma unroll 2
    for (int kk = 0; kk < 16; kk++){
      float4 xv = xp[kk];
      #pragma unroll
      for (int i = 0; i < 4; i++){
        float xi = f4g(xv, i);
        const float* w = sw + (kk*4+i)*152;
        a0 += xi * w[j];
        a1 += xi * w[64 + j];
        if (j < 24) a2 += xi * w[128 + j];
      }
    }
    P0[(long)n*152 + j] = a0;
    P0[(long)n*152 + 64 + j] = a1;
    if (j < 24) P0[(long)n*152 + 128 + j] = a2;
  }
}

// generic per-node GEMM: out[n][c] = scale * sum_k in[n][k]*W[k*ldw+c], c<C
template<int C>
__global__ void __launch_bounds__(256) k_node_mm(const float* __restrict__ in,
    const float* __restrict__ W, int ldw, float scale, float* __restrict__ out){
  __shared__ float sw[64*C];
  for (int i = threadIdx.x; i < 64*C; i += 256){
    int k = i / C, c = i - k*C;
    sw[i] = W[k*ldw + c] * scale;
  }
  __syncthreads();
  const int j = threadIdx.x & 63;
  constexpr int G = (C + 63)/64;
  int wid = blockIdx.x*4 + (threadIdx.x >> 6);
  int nw = gridDim.x*4;
  for (int n = wid; n < N_NODES; n += nw){
    const float4* xp = (const float4*)(in + (long)n*LAT);
    float acc[G];
    #pragma unroll
    for (int g = 0; g < G; g++) acc[g] = 0.f;
    #pragma unroll 2
    for (int kk = 0; kk < 16; kk++){
      float4 xv = xp[kk];
      #pragma unroll
      for (int i = 0; i < 4; i++){
        float xi = f4g(xv, i);
        int k = kk*4 + i;
        #pragma unroll
        for (int g = 0; g < G; g++){
          int c = g*64 + j;
          if (c < C) acc[g] += xi * sw[k*C + c];
        }
      }
    }
    #pragma unroll
    for (int g = 0; g < G; g++){
      int c = g*64 + j;
      if (c < C) out[(long)n*C + c] = acc[g];
    }
  }
}

// K4: fused tij. Phase1: t = LN(tA[c]+tB[nb]+phi@W3); phase2: edge_out=t@Wtij/8,
// w0 = (t@Wt0)*hh0[nb]*0.125 -> Xacc. LDS 28KB -> 5 blk/CU.
__global__ void __launch_bounds__(256,5) k_tij(
    const float* __restrict__ P0, const float* __restrict__ phi,
    const float* __restrict__ sph,
    const float* __restrict__ Wtcat,
    const float* __restrict__ lg, const float* __restrict__ lb,
    const float* __restrict__ Wtij, const float* __restrict__ Wt0,
    const int* __restrict__ ec, const int* __restrict__ en,
    float* __restrict__ T, float* __restrict__ Xacc,
    float* __restrict__ edge_out){
  __shared__ float sW3[8*64];
  __shared__ float swij[64*64];
  __shared__ float sw0[64*24];
  __shared__ float tst[4][4][64];
  for (int i = threadIdx.x; i < 8*64;  i += 256) sW3[i] = Wtcat[128*64 + i] * RS136;
  for (int i = threadIdx.x; i < 64*64; i += 256) swij[i] = Wtij[i];
  for (int i = threadIdx.x; i < 64*24; i += 256) sw0[i] = Wt0[i];
  __syncthreads();
  const int j = threadIdx.x & 63, lw = threadIdx.x >> 6;
  const float gj = lg[j], bj = lb[j];
  const int jc = (j < 24) ? j : 0;
  int wid = blockIdx.x*4 + lw;
  int nw  = gridDim.x*4;
  for (int p = wid; p < N_EDGES/4; p += nw){
    const int eb = p*4;
    int4 cv = *(const int4*)(ec + eb);
    int4 nv = *(const int4*)(en + eb);
    int ccs[4], nns[4];
    ccs[0] = __builtin_amdgcn_readfirstlane(cv.x);
    ccs[1] = __builtin_amdgcn_readfirstlane(cv.y);
    ccs[2] = __builtin_amdgcn_readfirstlane(cv.z);
    ccs[3] = __builtin_amdgcn_readfirstlane(cv.w);
    nns[0] = __builtin_amdgcn_readfirstlane(nv.x);
    nns[1] = __builtin_amdgcn_readfirstlane(nv.y);
    nns[2] = __builtin_amdgcn_readfirstlane(nv.z);
    nns[3] = __builtin_amdgcn_readfirstlane(nv.w);
    // phase 1: gather + phi GEMV + LN
    float a[4];
    #pragma unroll
    for (int x = 0; x < 4; x++)
      a[x] = P0[(long)ccs[x]*152 + j] + P0[(long)nns[x]*152 + 64 + j];
    const float4* ph = (const float4*)(phi + (long)eb*D_RAD);
    #pragma unroll
    for (int kk = 0; kk < 2; kk++){
      float4 p0=ph[kk], p1=ph[2+kk], p2=ph[4+kk], p3=ph[6+kk];
      #pragma unroll
      for (int i = 0; i < 4; i++){
        float u = sW3[(kk*4+i)*64 + j];
        a[0]+=f4g(p0,i)*u; a[1]+=f4g(p1,i)*u; a[2]+=f4g(p2,i)*u; a[3]+=f4g(p3,i)*u;
      }
    }
    #pragma unroll
    for (int x = 0; x < 4; x++){
      float acc = a[x];
      float mu = wave_sum(acc) * (1.f/64.f);
      float va = wave_sum(acc*acc) * (1.f/64.f) - mu*mu;
      float t = (acc - mu) * rsqrtf(va + 1e-5f) * gj + bj;
      T[(long)(eb+x)*LAT + j] = t;
      tst[lw][x][j] = t;
    }
    __threadfence_block();
    // phase 2
    float hh[4];
    #pragma unroll
    for (int x = 0; x < 4; x++) hh[x] = P0[(long)nns[x]*152 + 128 + jc];
    float eo[4]={0,0,0,0}, av[4]={0,0,0,0};
    #pragma unroll 2
    for (int kk = 0; kk < 16; kk++){
      float4 tv0 = *(const float4*)&tst[lw][0][kk*4];
      float4 tv1 = *(const float4*)&tst[lw][1][kk*4];
      float4 tv2 = *(const float4*)&tst[lw][2][kk*4];
      float4 tv3 = *(const float4*)&tst[lw][3][kk*4];
      #pragma unroll
      for (int i = 0; i < 4; i++){
        float u = swij[(kk*4+i)*64 + j];
        float w = sw0[(kk*4+i)*24 + jc];
        eo[0]+=f4g(tv0,i)*u; av[0]+=f4g(tv0,i)*w;
        eo[1]+=f4g(tv1,i)*u; av[1]+=f4g(tv1,i)*w;
        eo[2]+=f4g(tv2,i)*u; av[2]+=f4g(tv2,i)*w;
        eo[3]+=f4g(tv3,i)*u; av[3]+=f4g(tv3,i)*w;
      }
    }
    float w0s[4];
    #pragma unroll
    for (int x = 0; x < 4; x++){
      edge_out[(long)(eb+x)*LAT + j] = eo[x] * 0.125f;
      w0s[x] = av[x] * hh[x] * 0.125f;
    }
    #pragma unroll
    for (int x = 0; x < 4; x++){
      #pragma unroll
      for (int rep = 0; rep < 2; rep++){
        int tt = j + rep*64;
        int m = tt/9, d = tt - (tt/9)*9;
        int wi = (tt < 72) ? (irrep_of(d)*NHEAD + m) : 0;
        float wv = __shfl(w0s[x], wi);
        if (tt < 72){
          atomicAdd(&Xacc[ccs[x]*72 + tt], sph[(long)(eb+x)*D_SPH + d] * wv);
        }
      }
    }
    __threadfence_block();
  }
}

// K5: X = so3_norm(Xacc)
__global__ void k_node_X0(const float* __restrict__ Xacc, float* __restrict__ X){
  int n = blockIdx.x*(blockDim.x >> 6) + (threadIdx.x >> 6);
  int j = threadIdx.x & 63;
  if (n >= N_NODES) return;
  float x0 = Xacc[n*72 + j];
  float x1 = (j < 8) ? Xacc[n*72 + 64 + j] : 0.f;
  float s0 = 0.f, s1 = 0.f, s2 = 0.f;
  { int d = j % 9; int k3 = irrep_of(d);
    if (k3 == 0) s0 = x0*x0; else if (k3 == 1) s1 = x0*x0; else s2 = x0*x0; }
  if (j < 8){ int d = (64 + j) % 9; int k3 = irrep_of(d);
    if (k3 == 0) s0 += x1*x1; else if (k3 == 1) s1 += x1*x1; else s2 += x1*x1; }
  s0 = wave_sum(s0); s1 = wave_sum(s1); s2 = wave_sum(s2);
  float sa = rsqrtf(s0*0.125f + 1e-5f), sb = rsqrtf(s1*0.125f + 1e-5f), sc = rsqrtf(s2*0.125f + 1e-5f);
  { int d = j % 9; int k3 = irrep_of(d);
    X[n*72 + j] = x0 * (k3==0 ? sa : (k3==1 ? sb : sc)); }
  if (j < 8){ int d = (64 + j) % 9; int k3 = irrep_of(d);
    X[n*72 + 64 + j] = x1 * (k3==0 ? sa : (k3==1 ? sb : sc)); }
}

// K6: attention logits + running max. Q = t@Wq per-edge; K gathered from Hk.
// LDS 32KB -> 4 blk/CU.
__global__ void __launch_bounds__(256,4) k_att(const float* __restrict__ T, const float* __restrict__ Hk,
                     const float* __restrict__ Wq,
                     const int* __restrict__ ec, const int* __restrict__ en,
                     float* __restrict__ att, float* __restrict__ attmax){
  __shared__ float sq[64*128];
  for (int i = threadIdx.x; i < 64*128; i += 256) sq[i] = Wq[i];
  __syncthreads();
  const int j = threadIdx.x & 63;
  int wid = blockIdx.x*4 + (threadIdx.x >> 6);
  int nw  = gridDim.x*4;
  for (int p = wid; p < N_EDGES/4; p += nw){
    const int eb = p*4;
    int4 cv = *(const int4*)(ec + eb);
    int4 nv = *(const int4*)(en + eb);
    int ccs[4], nns[4];
    ccs[0] = __builtin_amdgcn_readfirstlane(cv.x);
    ccs[1] = __builtin_amdgcn_readfirstlane(cv.y);
    ccs[2] = __builtin_amdgcn_readfirstlane(cv.z);
    ccs[3] = __builtin_amdgcn_readfirstlane(cv.w);
    nns[0] = __builtin_amdgcn_readfirstlane(nv.x);
    nns[1] = __builtin_amdgcn_readfirstlane(nv.y);
    nns[2] = __builtin_amdgcn_readfirstlane(nv.z);
    nns[3] = __builtin_amdgcn_readfirstlane(nv.w);
    const float4* tp0 = (const float4*)(T + (long)(eb+0)*LAT);
    const float4* tp1 = (const float4*)(T + (long)(eb+1)*LAT);
    const float4* tp2 = (const float4*)(T + (long)(eb+2)*LAT);
    const float4* tp3 = (const float4*)(T + (long)(eb+3)*LAT);
    float qa[4]={0,0,0,0}, qb[4]={0,0,0,0};
    #pragma unroll 2
    for (int kk = 0; kk < 16; kk++){
      float4 tv[4] = {tp0[kk], tp1[kk], tp2[kk], tp3[kk]};
      const float* wq = sq + (kk*4)*128 + j;
      #pragma unroll
      for (int i = 0; i < 4; i++){
        float q0 = wq[i*128], q1 = wq[i*128 + 64];
        #pragma unroll
        for (int x = 0; x < 4; x++){
          float tx = f4g(tv[x], i);
          qa[x] += tx*q0; qb[x] += tx*q1;
        }
      }
    }
    float pa[4], pb[4];
    #pragma unroll
    for (int x = 0; x < 4; x++){
      pa[x] = qa[x] * Hk[(long)nns[x]*128 + j];
      pb[x] = qb[x] * Hk[(long)nns[x]*128 + 64 + j];
    }
    #pragma unroll
    for (int off = 8; off; off >>= 1){
      #pragma unroll
      for (int x = 0; x < 4; x++){
        pa[x] += __shfl_xor(pa[x], off);
        pb[x] += __shfl_xor(pb[x], off);
      }
    }
    if ((j & 15) == 0){
      int m = j >> 4;
      #pragma unroll
      for (int x = 0; x < 4; x++){
        float A = 4.f*pa[x], B = 4.f*pb[x];
        att[(long)(eb+x)*NHEAD + m] = A;
        att[(long)(eb+x)*NHEAD + 4 + m] = B;
        atomicMaxF(&attmax[ccs[x]*NHEAD + m], A);
        atomicMaxF(&attmax[ccs[x]*NHEAD + 4 + m], B);
      }
    }
  }
}

// K7: env = (t@Wrs[:216]) * Hw[nb]; hacc/asum/Xacc scatter in one pass.
// Wrs in LDS [k][j*4+g] -> one ds_read_b128 per k. LDS 92KB.
__global__ void __launch_bounds__(512,2) k_env(
    const float* __restrict__ T, const float* __restrict__ Hw,
    const float* __restrict__ X,
    const float* __restrict__ Wrs,
    const float* __restrict__ sph,
    const float* __restrict__ att, const float* __restrict__ attmax,
    const int* __restrict__ ec, const int* __restrict__ en,
    float* __restrict__ hacc, float* __restrict__ asum,
    float* __restrict__ Xacc){
  __shared__ float srs[64*256];
  __shared__ float senv[8][4][216];
  __shared__ float sev[8][32];
  for (int i = threadIdx.x; i < 64*256; i += 512){
    int k = i >> 8, r = i & 255;
    int col = (r & 3)*64 + (r >> 2);
    srs[i] = (col < 216) ? Wrs[k*GEN_W + col] : 0.f;
  }
  __syncthreads();
  const int j = threadIdx.x & 63, lw = threadIdx.x >> 6;
  int wid = blockIdx.x*8 + lw;
  int nw  = gridDim.x*8;
  for (int p = wid; p < N_EDGES/4; p += nw){
    const int eb = p*4;
    int4 cv = *(const int4*)(ec + eb);
    int4 nv = *(const int4*)(en + eb);
    int c0 = __builtin_amdgcn_readfirstlane(cv.x);
    int c1 = __builtin_amdgcn_readfirstlane(cv.y);
    int c2 = __builtin_amdgcn_readfirstlane(cv.z);
    int c3 = __builtin_amdgcn_readfirstlane(cv.w);
    int n0 = __builtin_amdgcn_readfirstlane(nv.x);
    int n1 = __builtin_amdgcn_readfirstlane(nv.y);
    int n2 = __builtin_amdgcn_readfirstlane(nv.z);
    int n3 = __builtin_amdgcn_readfirstlane(nv.w);
    const float4* tp0 = (const float4*)(T + (long)(eb+0)*LAT);
    const float4* tp1 = (const float4*)(T + (long)(eb+1)*LAT);
    const float4* tp2 = (const float4*)(T + (long)(eb+2)*LAT);
    const float4* tp3 = (const float4*)(T + (long)(eb+3)*LAT);
    float4 aT[4];
    #pragma unroll
    for (int x = 0; x < 4; x++) aT[x] = make_float4(0.f,0.f,0.f,0.f);
    #pragma unroll 2
    for (int kk = 0; kk < 16; kk++){
      float4 tv[4] = {tp0[kk], tp1[kk], tp2[kk], tp3[kk]};
      #pragma unroll
      for (int i = 0; i < 4; i++){
        const float4 r4 = *(const float4*)(srs + (kk*4+i)*256 + j*4);
        #pragma unroll
        for (int x = 0; x < 4; x++){
          float tx = f4g(tv[x], i);
          aT[x].x += tx*r4.x; aT[x].y += tx*r4.y; aT[x].z += tx*r4.z; aT[x].w += tx*r4.w;
        }
      }
    }
    int ccs[4] = {c0, c1, c2, c3};
    int nns[4] = {n0, n1, n2, n3};
    #pragma unroll
    for (int x = 0; x < 4; x++){
      const float* hw = Hw + (long)nns[x]*216;
      float e0 = aT[x].x * hw[j];
      float e1 = aT[x].y * hw[64 + j];
      float e2 = aT[x].z * hw[128 + j];
      atomicAdd(&hacc[ccs[x]*LAT + j], e0);
      senv[lw][x][j] = e0;
      senv[lw][x][64 + j] = e1;
      senv[lw][x][128 + j] = e2;
      if (j < 24) senv[lw][x][192 + j] = aT[x].w * hw[192 + j];
    }
    if (j < 32){
      int x = j >> 3, m = j & 7;
      int cc = (x==0)?c0:((x==1)?c1:((x==2)?c2:c3));
      float ev = __expf(att[(long)(eb+x)*NHEAD + m] - attmax[cc*NHEAD + m]);
      sev[lw][j] = ev;
      atomicAdd(&asum[cc*NHEAD + m], ev);
    }
    __threadfence_block();
    #pragma unroll
    for (int x = 0; x < 4; x++){
      const long e = eb + x;
      const int cc = ccs[x];
      const float* Xr = X + (long)nns[x]*72;
      #pragma unroll
      for (int rep = 0; rep < 2; rep++){
        int tt = j + rep*64;
        if (tt < 72){
          int m = tt/9, d = tt - m*9, k3 = irrep_of(d);
          float ds = sph[e*D_SPH + d] * senv[lw][x][k3*8 + m];
          float dq = 0.f;
          #pragma unroll
          for (int i = 0; i < 8; i++) dq += Xr[i*9 + d] * senv[lw][x][24 + k3*64 + i*8 + m];
          float val = (ds + dq*RS8) * sev[lw][x*8 + m];
          atomicAdd(&Xacc[cc*72 + tt], val);
        }
      }
    }
    __threadfence_block();
  }
}

// K8: h = LN(h+hacc); X = so3_norm(X + Xacc/(attsum+1e-12))
__global__ void k_node_upd(const float* __restrict__ hacc, const float* __restrict__ attsum,
                           const float* __restrict__ Xacc,
                           const float* __restrict__ lg, const float* __restrict__ lb,
                           float* __restrict__ h, float* __restrict__ X){
  int n = blockIdx.x*(blockDim.x >> 6) + (threadIdx.x >> 6);
  int j = threadIdx.x & 63;
  if (n >= N_NODES) return;
  float hv = h[n*LAT + j] + hacc[n*LAT + j];
  float mu = wave_sum(hv) * (1.f/64.f);
  float va = wave_sum(hv*hv) * (1.f/64.f) - mu*mu;
  h[n*LAT + j] = (hv - mu) * rsqrtf(va + 1e-5f) * lg[j] + lb[j];

  float x0, x1 = 0.f;
  float s0 = 0.f, s1 = 0.f, s2 = 0.f;
  { int m = j/9, d = j - m*9;
    x0 = X[n*72 + j] + Xacc[n*72 + j] / (attsum[n*NHEAD + m] + 1e-12f);
    int k3 = irrep_of(d);
    if (k3 == 0) s0 = x0*x0; else if (k3 == 1) s1 = x0*x0; else s2 = x0*x0; }
  if (j < 8){ int tt = 64 + j; int m = tt/9, d = tt - m*9;
    x1 = X[n*72 + tt] + Xacc[n*72 + tt] / (attsum[n*NHEAD + m] + 1e-12f);
    int k3 = irrep_of(d);
    if (k3 == 0) s0 += x1*x1; else if (k3 == 1) s1 += x1*x1; else s2 += x1*x1; }
  s0 = wave_sum(s0); s1 = wave_sum(s1); s2 = wave_sum(s2);
  float sa = rsqrtf(s0*0.125f + 1e-5f), sb = rsqrtf(s1*0.125f + 1e-5f), sc = rsqrtf(s2*0.125f + 1e-5f);
  { int d = j % 9; int k3 = irrep_of(d);
    X[n*72 + j] = x0 * (k3==0 ? sa : (k3==1 ? sb : sc)); }
  if (j < 8){ int d = (64 + j) % 9; int k3 = irrep_of(d);
    X[n*72 + 64 + j] = x1 * (k3==0 ? sa : (k3==1 ? sb : sc)); }
}

// K9: w = h@W_hemb/8 -> (3,8,64); Xo = eq_linear(X,w); node_out
__global__ void k_node_out(const float* __restrict__ h, const float* __restrict__ X,
                           const float* __restrict__ Whemb,
                           float* __restrict__ out){
  __shared__ float sx[4][72];
  int n = blockIdx.x*(blockDim.x >> 6) + (threadIdx.x >> 6);
  int j = threadIdx.x & 63;
  int lw = threadIdx.x >> 6;
  if (n >= N_NODES) return;
  float hv = h[n*LAT + j];
  float wv[24];
  #pragma unroll
  for (int i = 0; i < 24; i++) wv[i] = 0.f;
  #pragma unroll 4
  for (int c = 0; c < LAT; c++){
    float hc = __shfl(hv, c);
    #pragma unroll
    for (int ki = 0; ki < 24; ki++)
      wv[ki] += hc * Whemb[c*1536 + ki*64 + j];
  }
  sx[lw][j] = X[n*72 + j];
  if (j < 8) sx[lw][64 + j] = X[n*72 + 64 + j];
  __threadfence_block();
  #pragma unroll
  for (int d = 0; d < 9; d++){
    int k3 = irrep_of(d);
    float acc = 0.f;
    #pragma unroll
    for (int i = 0; i < 8; i++) acc += sx[lw][i*9 + d] * wv[k3*8 + i];
    acc *= 0.125f * RS8;
    int pos;
    if (d == 0)      pos = n*576 + j;
    else if (d < 4)  pos = n*576 + 64  + j*3 + (d - 1);
    else             pos = n*576 + 256 + j*5 + (d - 4);
    out[pos] = acc;
  }
}

// ---- workspace layout (floats) — total 26.56M floats = 106.2 MB ----
static const long O_T    = 0;          // 20.48M  (E*64)
static const long O_ATT  = 20480000;   // 2.56M   (E*8) ; prologue pn/pc/mn/P0 alias here
static const long O_H0   = 23040000;   // 640k
static const long O_H    = 23680000;   // 640k
static const long O_X    = 24320000;   // 720k
static const long O_XACC = 25040000;   // 720k
static const long O_HACC = 25760000;   // 640k
static const long O_AMAX = 26400000;   // 80k
static const long O_ASUM = 26480000;   // 80k

extern "C" void kernel_launch(void* const* d_in, const int* in_sizes, int n_in,
                              void* d_out, int out_size, void* d_ws, size_t ws_size,
                              hipStream_t stream) {
  const float* na    = (const float*)d_in[0];
  const float* phi   = (const float*)d_in[1];
  const float* sph   = (const float*)d_in[2];
  const float* Wn    = (const float*)d_in[4];
  const float* Wc    = (const float*)d_in[5];
  const float* Wcat  = (const float*)d_in[6];
  const float* We    = (const float*)d_in[7];
  const float* ln0g  = (const float*)d_in[8];
  const float* ln0b  = (const float*)d_in[9];
  const float* lneg  = (const float*)d_in[10];
  const float* lneb  = (const float*)d_in[11];
  const float* Wtcat = (const float*)d_in[12];
  const float* Wt0   = (const float*)d_in[13];
  const float* Wh0   = (const float*)d_in[14];
  const float* Wrs   = (const float*)d_in[15];
  const float* Whj   = (const float*)d_in[16];
  const float* lnlg  = (const float*)d_in[17];
  const float* lnlb  = (const float*)d_in[18];
  const float* Wq    = (const float*)d_in[19];
  const float* Wk    = (const float*)d_in[20];
  const float* Whemb = (const float*)d_in[21];
  const float* Wtij  = (const float*)d_in[22];
  const int* ec = (const int*)d_in[23];
  const int* en = (const int*)d_in[24];

  float* ws   = (float*)d_ws;
  float* T    = ws + O_T;
  float* att  = ws + O_ATT;
  float* h0   = ws + O_H0;
  float* h    = ws + O_H;
  float* X    = ws + O_X;
  float* Xacc = ws + O_XACC;
  float* hacc = ws + O_HACC;
  float* amax = ws + O_AMAX;
  float* asum = ws + O_ASUM;
  // prologue-only buffers alias the att region (dead before k_att runs)
  float* pn   = att;
  float* pc   = att + 640000;
  float* mn   = att + 1280000;
  float* P0   = att;               // 1.52M, written after pn/pc/mn are dead

  float* out      = (float*)d_out;
  float* edge_out = out + (long)N_NODES*576;
  // per-layer node precomputes scratch in node_out region (written only at end)
  float* Hk = out;                 // 1.28M
  float* Hw = out + 1280000;       // 2.16M

  hipMemsetAsync(mn,   0, 640000*sizeof(float), stream);
  hipMemsetAsync(Xacc, 0, 720000*sizeof(float), stream);

  k_node_proj<<<(N_NODES*64)/256, 256, 0, stream>>>(na, Wn, Wc, pn, pc);
  k_edge_msg<<<1024, 256, 0, stream>>>(phi, We, ec, en, pn, mn);
  k_node_h<<<N_NODES/4, 256, 0, stream>>>(pc, mn, Wcat, ln0g, ln0b, h0, h);
  k_pre0<<<256, 256, 0, stream>>>(h0, Wtcat, Wh0, P0);
  k_tij<<<1024, 256, 0, stream>>>(P0, phi, sph, Wtcat, lneg, lneb, Wtij, Wt0,
                                  ec, en, T, Xacc, edge_out);
  k_node_X0<<<N_NODES/4, 256, 0, stream>>>(Xacc, X);

  for (int l = 0; l < NL; l++){
    hipMemsetAsync(hacc, 0, 640000*sizeof(float), stream);
    hipMemsetAsync(Xacc, 0, 720000*sizeof(float), stream);
    hipMemsetAsync(asum, 0, 80000*sizeof(float), stream);
    fill_neg_inf<<<(80000 + 255)/256, 256, 0, stream>>>(amax, 80000);

    k_node_mm<128><<<512, 256, 0, stream>>>(h, Wk + l*64*128, 128, 1.f, Hk);
    k_node_mm<216><<<512, 256, 0, stream>>>(h, Whj + (long)l*64*GEN_W, GEN_W, 0.125f, Hw);
    k_att<<<1024, 256, 0, stream>>>(T, Hk, Wq + l*64*128, ec, en, att, amax);
    k_env<<<256, 512, 0, stream>>>(T, Hw, X, Wrs + (long)l*64*GEN_W, sph,
                                   att, amax, ec, en, hacc, asum, Xacc);
    k_node_upd<<<N_NODES/4, 256, 0, stream>>>(hacc, asum, Xacc, lnlg + l*64, lnlb + l*64, h, X);
  }

  k_node_out<<<N_NODES/4, 256, 0, stream>>>(h, X, Whemb, out);
}

// Round 5
// 1841.428 us; speedup vs baseline: 3.0773x; 1.1602x over previous
//
#include <hip/hip_runtime.h>
#include <hip/hip_bf16.h>

#define N_NODES 10000
#define N_EDGES 320000
#define D_NODE 32
#define D_RAD 8
#define D_SPH 9
#define LAT 64
#define NHEAD 8
#define NL 2
#define GEN_W 280
#define WN_ENV 24

#define RS136 0.08574929257125442f   // 136^-0.5
#define RS8   0.35355339059327373f   // 8^-0.5

static_assert(N_EDGES % 4 == 0, "edge quads");

__device__ __forceinline__ int irrep_of(int d){ return (d==0)?0:((d<4)?1:2); }

__device__ __forceinline__ float wave_sum(float v){
  #pragma unroll
  for (int off=32; off; off>>=1) v += __shfl_xor(v, off);
  return v;
}

__device__ __forceinline__ void atomicMaxF(float* addr, float v){
  if (v >= 0.f) atomicMax((int*)addr, __float_as_int(v));
  else          atomicMin((unsigned int*)addr, __float_as_uint(v));
}

__device__ __forceinline__ float f4g(const float4& v, int i){
  return (i==0)?v.x:((i==1)?v.y:((i==2)?v.z:v.w));
}

__global__ void fill_neg_inf(float* p, int n){
  int i = blockIdx.x*blockDim.x + threadIdx.x;
  if (i < n) p[i] = __uint_as_float(0xff800000u);
}

// K1: pn = na@W_node, pc = na@W_center
__global__ void k_node_proj(const float* __restrict__ na,
                            const float* __restrict__ Wn,
                            const float* __restrict__ Wc,
                            float* __restrict__ pn, float* __restrict__ pc){
  int idx = blockIdx.x*blockDim.x + threadIdx.x;
  int n = idx >> 6, j = idx & 63;
  if (n >= N_NODES) return;
  float an = 0.f, ac = 0.f;
  #pragma unroll
  for (int k = 0; k < D_NODE; k++){
    float a = na[n*D_NODE + k];
    an += a * Wn[k*LAT + j];
    ac += a * Wc[k*LAT + j];
  }
  pn[idx] = an; pc[idx] = ac;
}

// K2: pe = pn[nb] * (phi@W_edge); m_node = segsum(pe). E=4, We in LDS.
__global__ void __launch_bounds__(256,4) k_edge_msg(const float* __restrict__ phi,
                           const float* __restrict__ We,
                           const int* __restrict__ ec, const int* __restrict__ en,
                           const float* __restrict__ pn, float* __restrict__ mnode){
  __shared__ float swe[8*64];
  for (int i = threadIdx.x; i < 8*64; i += 256) swe[i] = We[i];
  __syncthreads();
  const int j = threadIdx.x & 63;
  int wid = blockIdx.x*4 + (threadIdx.x >> 6);
  int nw  = gridDim.x*4;
  for (int p = wid; p < N_EDGES/4; p += nw){
    const int eb = p*4;
    int4 cv = *(const int4*)(ec + eb);
    int4 nv = *(const int4*)(en + eb);
    int c0 = __builtin_amdgcn_readfirstlane(cv.x);
    int c1 = __builtin_amdgcn_readfirstlane(cv.y);
    int c2 = __builtin_amdgcn_readfirstlane(cv.z);
    int c3 = __builtin_amdgcn_readfirstlane(cv.w);
    int n0 = __builtin_amdgcn_readfirstlane(nv.x);
    int n1 = __builtin_amdgcn_readfirstlane(nv.y);
    int n2 = __builtin_amdgcn_readfirstlane(nv.z);
    int n3 = __builtin_amdgcn_readfirstlane(nv.w);
    const float4* ph = (const float4*)(phi + (long)eb*D_RAD);
    float d0=0.f, d1=0.f, d2=0.f, d3=0.f;
    #pragma unroll
    for (int kk = 0; kk < 2; kk++){
      float4 p0=ph[kk], p1=ph[2+kk], p2=ph[4+kk], p3=ph[6+kk];
      #pragma unroll
      for (int i = 0; i < 4; i++){
        float u = swe[(kk*4+i)*64 + j];
        d0+=f4g(p0,i)*u; d1+=f4g(p1,i)*u; d2+=f4g(p2,i)*u; d3+=f4g(p3,i)*u;
      }
    }
    atomicAdd(&mnode[(long)c0*LAT + j], pn[(long)n0*LAT + j] * d0);
    atomicAdd(&mnode[(long)c1*LAT + j], pn[(long)n1*LAT + j] * d1);
    atomicAdd(&mnode[(long)c2*LAT + j], pn[(long)n2*LAT + j] * d2);
    atomicAdd(&mnode[(long)c3*LAT + j], pn[(long)n3*LAT + j] * d3);
  }
}

// K3: h0 = h = LN([pc, m_node]@W_concat)
__global__ void k_node_h(const float* __restrict__ pc, const float* __restrict__ mnode,
                         const float* __restrict__ Wcat,
                         const float* __restrict__ g, const float* __restrict__ b,
                         float* __restrict__ h0, float* __restrict__ h){
  int n = blockIdx.x*(blockDim.x >> 6) + (threadIdx.x >> 6);
  int j = threadIdx.x & 63;
  if (n >= N_NODES) return;
  float acc = 0.f;
  for (int k = 0; k < LAT; k++) acc += pc[n*LAT + k] * Wcat[k*LAT + j];
  for (int k = 0; k < LAT; k++) acc += mnode[n*LAT + k] * Wcat[(LAT + k)*LAT + j];
  float mu = wave_sum(acc) * (1.f/64.f);
  float va = wave_sum(acc*acc) * (1.f/64.f) - mu*mu;
  float v = (acc - mu) * rsqrtf(va + 1e-5f) * g[j] + b[j];
  h0[n*LAT + j] = v; h[n*LAT + j] = v;
}

// K3b: P0[n] = [ h0@Wtcat[0:64]*RS136 | h0@Wtcat[64:128]*RS136 | h0@Wh0*0.125 ]
__global__ void __launch_bounds__(256) k_pre0(const float* __restrict__ h0,
                       const float* __restrict__ Wtcat, const float* __restrict__ Wh0,
                       float* __restrict__ P0){
  __shared__ float sw[64*152];
  for (int i = threadIdx.x; i < 64*152; i += 256){
    int k = i / 152, c = i - k*152;
    float v;
    if (c < 64)       v = Wtcat[k*64 + c] * RS136;
    else if (c < 128) v = Wtcat[(64 + k)*64 + (c - 64)] * RS136;
    else              v = Wh0[k*24 + (c - 128)] * 0.125f;
    sw[i] = v;
  }
  __syncthreads();
  const int j = threadIdx.x & 63;
  int wid = blockIdx.x*4 + (threadIdx.x >> 6);
  int nw = gridDim.x*4;
  for (int n = wid; n < N_NODES; n += nw){
    const float4* xp = (const float4*)(h0 + (long)n*LAT);
    float a0=0.f, a1=0.f, a2=0.f;
    #pragma unroll 2
    for (int kk = 0; kk < 16; kk++){
      float4 xv = xp[kk];
      #pragma unroll
      for (int i = 0; i < 4; i++){
        float xi = f4g(xv, i);
        const float* w = sw + (kk*4+i)*152;
        a0 += xi * w[j];
        a1 += xi * w[64 + j];
        if (j < 24) a2 += xi * w[128 + j];
      }
    }
    P0[(long)n*152 + j] = a0;
    P0[(long)n*152 + 64 + j] = a1;
    if (j < 24) P0[(long)n*152 + 128 + j] = a2;
  }
}

// generic per-node GEMM: out[n][c] = scale * sum_k in[n][k]*W[k*ldw+c], c<C
template<int C>
__global__ void __launch_bounds__(256) k_node_mm(const float* __restrict__ in,
    const float* __restrict__ W, int ldw, float scale, float* __restrict__ out){
  __shared__ float sw[64*C];
  for (int i = threadIdx.x; i < 64*C; i += 256){
    int k = i / C, c = i - k*C;
    sw[i] = W[k*ldw + c] * scale;
  }
  __syncthreads();
  const int j = threadIdx.x & 63;
  constexpr int G = (C + 63)/64;
  int wid = blockIdx.x*4 + (threadIdx.x >> 6);
  int nw = gridDim.x*4;
  for (int n = wid; n < N_NODES; n += nw){
    const float4* xp = (const float4*)(in + (long)n*LAT);
    float acc[G];
    #pragma unroll
    for (int g = 0; g < G; g++) acc[g] = 0.f;
    #pragma unroll 2
    for (int kk = 0; kk < 16; kk++){
      float4 xv = xp[kk];
      #pragma unroll
      for (int i = 0; i < 4; i++){
        float xi = f4g(xv, i);
        int k = kk*4 + i;
        #pragma unroll
        for (int g = 0; g < G; g++){
          int c = g*64 + j;
          if (c < C) acc[g] += xi * sw[k*C + c];
        }
      }
    }
    #pragma unroll
    for (int g = 0; g < G; g++){
      int c = g*64 + j;
      if (c < C) out[(long)n*C + c] = acc[g];
    }
  }
}

// K4: fused tij. Phase1: t = LN(tA[c]+tB[nb]+phi@W3); phase2: edge_out=t@Wtij/8,
// w0 = (t@Wt0)*hh0[nb]*0.125 -> Xacc. LDS 28KB -> 5 blk/CU. No fences (per-wave LDS).
__global__ void __launch_bounds__(256,5) k_tij(
    const float* __restrict__ P0, const float* __restrict__ phi,
    const float* __restrict__ sph,
    const float* __restrict__ Wtcat,
    const float* __restrict__ lg, const float* __restrict__ lb,
    const float* __restrict__ Wtij, const float* __restrict__ Wt0,
    const int* __restrict__ ec, const int* __restrict__ en,
    float* __restrict__ T, float* __restrict__ Xacc,
    float* __restrict__ edge_out){
  __shared__ float sW3[8*64];
  __shared__ float swij[64*64];
  __shared__ float sw0[64*24];
  __shared__ float tst[4][4][64];
  for (int i = threadIdx.x; i < 8*64;  i += 256) sW3[i] = Wtcat[128*64 + i] * RS136;
  for (int i = threadIdx.x; i < 64*64; i += 256) swij[i] = Wtij[i];
  for (int i = threadIdx.x; i < 64*24; i += 256) sw0[i] = Wt0[i];
  __syncthreads();
  const int j = threadIdx.x & 63, lw = threadIdx.x >> 6;
  const float gj = lg[j], bj = lb[j];
  const int jc = (j < 24) ? j : 0;
  int wid = blockIdx.x*4 + lw;
  int nw  = gridDim.x*4;
  for (int p = wid; p < N_EDGES/4; p += nw){
    const int eb = p*4;
    int4 cv = *(const int4*)(ec + eb);
    int4 nv = *(const int4*)(en + eb);
    int ccs[4], nns[4];
    ccs[0] = __builtin_amdgcn_readfirstlane(cv.x);
    ccs[1] = __builtin_amdgcn_readfirstlane(cv.y);
    ccs[2] = __builtin_amdgcn_readfirstlane(cv.z);
    ccs[3] = __builtin_amdgcn_readfirstlane(cv.w);
    nns[0] = __builtin_amdgcn_readfirstlane(nv.x);
    nns[1] = __builtin_amdgcn_readfirstlane(nv.y);
    nns[2] = __builtin_amdgcn_readfirstlane(nv.z);
    nns[3] = __builtin_amdgcn_readfirstlane(nv.w);
    // phase 1: gather + phi GEMV + LN
    float a[4];
    #pragma unroll
    for (int x = 0; x < 4; x++)
      a[x] = P0[(long)ccs[x]*152 + j] + P0[(long)nns[x]*152 + 64 + j];
    const float4* ph = (const float4*)(phi + (long)eb*D_RAD);
    #pragma unroll
    for (int kk = 0; kk < 2; kk++){
      float4 p0=ph[kk], p1=ph[2+kk], p2=ph[4+kk], p3=ph[6+kk];
      #pragma unroll
      for (int i = 0; i < 4; i++){
        float u = sW3[(kk*4+i)*64 + j];
        a[0]+=f4g(p0,i)*u; a[1]+=f4g(p1,i)*u; a[2]+=f4g(p2,i)*u; a[3]+=f4g(p3,i)*u;
      }
    }
    #pragma unroll
    for (int x = 0; x < 4; x++){
      float acc = a[x];
      float mu = wave_sum(acc) * (1.f/64.f);
      float va = wave_sum(acc*acc) * (1.f/64.f) - mu*mu;
      float t = (acc - mu) * rsqrtf(va + 1e-5f) * gj + bj;
      T[(long)(eb+x)*LAT + j] = t;
      tst[lw][x][j] = t;
    }
    // phase 2 (tst same-wave DS: in-order, no fence needed)
    float hh[4];
    #pragma unroll
    for (int x = 0; x < 4; x++) hh[x] = P0[(long)nns[x]*152 + 128 + jc];
    float eo[4]={0,0,0,0}, av[4]={0,0,0,0};
    #pragma unroll 2
    for (int kk = 0; kk < 16; kk++){
      float4 tv0 = *(const float4*)&tst[lw][0][kk*4];
      float4 tv1 = *(const float4*)&tst[lw][1][kk*4];
      float4 tv2 = *(const float4*)&tst[lw][2][kk*4];
      float4 tv3 = *(const float4*)&tst[lw][3][kk*4];
      #pragma unroll
      for (int i = 0; i < 4; i++){
        float u = swij[(kk*4+i)*64 + j];
        float w = sw0[(kk*4+i)*24 + jc];
        eo[0]+=f4g(tv0,i)*u; av[0]+=f4g(tv0,i)*w;
        eo[1]+=f4g(tv1,i)*u; av[1]+=f4g(tv1,i)*w;
        eo[2]+=f4g(tv2,i)*u; av[2]+=f4g(tv2,i)*w;
        eo[3]+=f4g(tv3,i)*u; av[3]+=f4g(tv3,i)*w;
      }
    }
    float w0s[4];
    #pragma unroll
    for (int x = 0; x < 4; x++){
      edge_out[(long)(eb+x)*LAT + j] = eo[x] * 0.125f;
      w0s[x] = av[x] * hh[x] * 0.125f;
    }
    #pragma unroll
    for (int x = 0; x < 4; x++){
      #pragma unroll
      for (int rep = 0; rep < 2; rep++){
        int tt = j + rep*64;
        int m = tt/9, d = tt - (tt/9)*9;
        int wi = (tt < 72) ? (irrep_of(d)*NHEAD + m) : 0;
        float wv = __shfl(w0s[x], wi);
        if (tt < 72){
          atomicAdd(&Xacc[ccs[x]*72 + tt], sph[(long)(eb+x)*D_SPH + d] * wv);
        }
      }
    }
  }
}

// K5: X = so3_norm(Xacc)
__global__ void k_node_X0(const float* __restrict__ Xacc, float* __restrict__ X){
  int n = blockIdx.x*(blockDim.x >> 6) + (threadIdx.x >> 6);
  int j = threadIdx.x & 63;
  if (n >= N_NODES) return;
  float x0 = Xacc[n*72 + j];
  float x1 = (j < 8) ? Xacc[n*72 + 64 + j] : 0.f;
  float s0 = 0.f, s1 = 0.f, s2 = 0.f;
  { int d = j % 9; int k3 = irrep_of(d);
    if (k3 == 0) s0 = x0*x0; else if (k3 == 1) s1 = x0*x0; else s2 = x0*x0; }
  if (j < 8){ int d = (64 + j) % 9; int k3 = irrep_of(d);
    if (k3 == 0) s0 += x1*x1; else if (k3 == 1) s1 += x1*x1; else s2 += x1*x1; }
  s0 = wave_sum(s0); s1 = wave_sum(s1); s2 = wave_sum(s2);
  float sa = rsqrtf(s0*0.125f + 1e-5f), sb = rsqrtf(s1*0.125f + 1e-5f), sc = rsqrtf(s2*0.125f + 1e-5f);
  { int d = j % 9; int k3 = irrep_of(d);
    X[n*72 + j] = x0 * (k3==0 ? sa : (k3==1 ? sb : sc)); }
  if (j < 8){ int d = (64 + j) % 9; int k3 = irrep_of(d);
    X[n*72 + 64 + j] = x1 * (k3==0 ? sa : (k3==1 ? sb : sc)); }
}

// K6: attention logits + running max. Q = t@Wq per-edge; K gathered from Hk.
// LDS 32KB -> 4 blk/CU.
__global__ void __launch_bounds__(256,4) k_att(const float* __restrict__ T, const float* __restrict__ Hk,
                     const float* __restrict__ Wq,
                     const int* __restrict__ ec, const int* __restrict__ en,
                     float* __restrict__ att, float* __restrict__ attmax){
  __shared__ float sq[64*128];
  for (int i = threadIdx.x; i < 64*128; i += 256) sq[i] = Wq[i];
  __syncthreads();
  const int j = threadIdx.x & 63;
  int wid = blockIdx.x*4 + (threadIdx.x >> 6);
  int nw  = gridDim.x*4;
  for (int p = wid; p < N_EDGES/4; p += nw){
    const int eb = p*4;
    int4 cv = *(const int4*)(ec + eb);
    int4 nv = *(const int4*)(en + eb);
    int ccs[4], nns[4];
    ccs[0] = __builtin_amdgcn_readfirstlane(cv.x);
    ccs[1] = __builtin_amdgcn_readfirstlane(cv.y);
    ccs[2] = __builtin_amdgcn_readfirstlane(cv.z);
    ccs[3] = __builtin_amdgcn_readfirstlane(cv.w);
    nns[0] = __builtin_amdgcn_readfirstlane(nv.x);
    nns[1] = __builtin_amdgcn_readfirstlane(nv.y);
    nns[2] = __builtin_amdgcn_readfirstlane(nv.z);
    nns[3] = __builtin_amdgcn_readfirstlane(nv.w);
    const float4* tp0 = (const float4*)(T + (long)(eb+0)*LAT);
    const float4* tp1 = (const float4*)(T + (long)(eb+1)*LAT);
    const float4* tp2 = (const float4*)(T + (long)(eb+2)*LAT);
    const float4* tp3 = (const float4*)(T + (long)(eb+3)*LAT);
    float qa[4]={0,0,0,0}, qb[4]={0,0,0,0};
    #pragma unroll 2
    for (int kk = 0; kk < 16; kk++){
      float4 tv[4] = {tp0[kk], tp1[kk], tp2[kk], tp3[kk]};
      const float* wq = sq + (kk*4)*128 + j;
      #pragma unroll
      for (int i = 0; i < 4; i++){
        float q0 = wq[i*128], q1 = wq[i*128 + 64];
        #pragma unroll
        for (int x = 0; x < 4; x++){
          float tx = f4g(tv[x], i);
          qa[x] += tx*q0; qb[x] += tx*q1;
        }
      }
    }
    float pa[4], pb[4];
    #pragma unroll
    for (int x = 0; x < 4; x++){
      pa[x] = qa[x] * Hk[(long)nns[x]*128 + j];
      pb[x] = qb[x] * Hk[(long)nns[x]*128 + 64 + j];
    }
    #pragma unroll
    for (int off = 8; off; off >>= 1){
      #pragma unroll
      for (int x = 0; x < 4; x++){
        pa[x] += __shfl_xor(pa[x], off);
        pb[x] += __shfl_xor(pb[x], off);
      }
    }
    if ((j & 15) == 0){
      int m = j >> 4;
      #pragma unroll
      for (int x = 0; x < 4; x++){
        float A = 4.f*pa[x], B = 4.f*pb[x];
        att[(long)(eb+x)*NHEAD + m] = A;
        att[(long)(eb+x)*NHEAD + 4 + m] = B;
        atomicMaxF(&attmax[ccs[x]*NHEAD + m], A);
        atomicMaxF(&attmax[ccs[x]*NHEAD + 4 + m], B);
      }
    }
  }
}

// K7: env = (t@Wrs[:216]) * Hw[nb]; hacc/asum/Xacc scatter in one pass.
// 1024 thr (16 waves) x 1 blk/CU; srs exact [64][216]; lane j<54 owns cols 4j..4j+3
// (float4 srs read + float4 Hw read + b128 senv write). X rows staged in LDS.
// No fences: senv/sev/sxn are per-wave, same-wave DS is in-order.
// LDS = 55296+55296+20480+2048 = 133120 B.
__global__ void __launch_bounds__(1024,4) k_env(
    const float* __restrict__ T, const float* __restrict__ Hw,
    const float* __restrict__ X,
    const float* __restrict__ Wrs,
    const float* __restrict__ sph,
    const float* __restrict__ att, const float* __restrict__ attmax,
    const int* __restrict__ ec, const int* __restrict__ en,
    float* __restrict__ hacc, float* __restrict__ asum,
    float* __restrict__ Xacc){
  __shared__ float srs[64*216];
  __shared__ float senv[16][4][216];
  __shared__ float sxn[16][4][80];
  __shared__ float sev[16][32];
  for (int i = threadIdx.x; i < 64*216; i += 1024){
    int k = i / 216, c = i - k*216;
    srs[i] = Wrs[k*GEN_W + c];
  }
  __syncthreads();
  const int j = threadIdx.x & 63, lw = threadIdx.x >> 6;
  int wid = blockIdx.x*16 + lw;
  int nw  = gridDim.x*16;
  for (int p = wid; p < N_EDGES/4; p += nw){
    const int eb = p*4;
    int4 cv = *(const int4*)(ec + eb);
    int4 nv = *(const int4*)(en + eb);
    int ccs[4], nns[4];
    ccs[0] = __builtin_amdgcn_readfirstlane(cv.x);
    ccs[1] = __builtin_amdgcn_readfirstlane(cv.y);
    ccs[2] = __builtin_amdgcn_readfirstlane(cv.z);
    ccs[3] = __builtin_amdgcn_readfirstlane(cv.w);
    nns[0] = __builtin_amdgcn_readfirstlane(nv.x);
    nns[1] = __builtin_amdgcn_readfirstlane(nv.y);
    nns[2] = __builtin_amdgcn_readfirstlane(nv.z);
    nns[3] = __builtin_amdgcn_readfirstlane(nv.w);
    // stage X rows (coalesced) for the d_eq gathers
    #pragma unroll
    for (int x = 0; x < 4; x++){
      const float* Xr = X + (long)nns[x]*72;
      sxn[lw][x][j] = Xr[j];
      if (j < 8) sxn[lw][x][64 + j] = Xr[64 + j];
    }
    const float4* tp0 = (const float4*)(T + (long)(eb+0)*LAT);
    const float4* tp1 = (const float4*)(T + (long)(eb+1)*LAT);
    const float4* tp2 = (const float4*)(T + (long)(eb+2)*LAT);
    const float4* tp3 = (const float4*)(T + (long)(eb+3)*LAT);
    float4 aT[4];
    #pragma unroll
    for (int x = 0; x < 4; x++) aT[x] = make_float4(0.f,0.f,0.f,0.f);
    if (j < 54){
      #pragma unroll 2
      for (int kk = 0; kk < 16; kk++){
        float4 tv[4] = {tp0[kk], tp1[kk], tp2[kk], tp3[kk]};
        #pragma unroll
        for (int i = 0; i < 4; i++){
          const float4 r4 = *(const float4*)(srs + (kk*4+i)*216 + j*4);
          #pragma unroll
          for (int x = 0; x < 4; x++){
            float tx = f4g(tv[x], i);
            aT[x].x += tx*r4.x; aT[x].y += tx*r4.y; aT[x].z += tx*r4.z; aT[x].w += tx*r4.w;
          }
        }
      }
      #pragma unroll
      for (int x = 0; x < 4; x++){
        const float4 hw4 = *(const float4*)(Hw + (long)nns[x]*216 + j*4);
        float4 ev4;
        ev4.x = aT[x].x * hw4.x;
        ev4.y = aT[x].y * hw4.y;
        ev4.z = aT[x].z * hw4.z;
        ev4.w = aT[x].w * hw4.w;
        *(float4*)&senv[lw][x][j*4] = ev4;
      }
    }
    if (j < 32){
      int x = j >> 3, m = j & 7;
      int cc = ccs[x];
      float ev = __expf(att[(long)(eb+x)*NHEAD + m] - attmax[cc*NHEAD + m]);
      sev[lw][j] = ev;
      atomicAdd(&asum[cc*NHEAD + m], ev);
    }
    // hacc from senv (same-wave DS in-order)
    #pragma unroll
    for (int x = 0; x < 4; x++){
      atomicAdd(&hacc[ccs[x]*LAT + j], senv[lw][x][j]);
    }
    #pragma unroll
    for (int x = 0; x < 4; x++){
      const long e = eb + x;
      const int cc = ccs[x];
      #pragma unroll
      for (int rep = 0; rep < 2; rep++){
        int tt = j + rep*64;
        if (tt < 72){
          int m = tt/9, d = tt - m*9, k3 = irrep_of(d);
          float ds = sph[e*D_SPH + d] * senv[lw][x][k3*8 + m];
          float dq = 0.f;
          #pragma unroll
          for (int i = 0; i < 8; i++) dq += sxn[lw][x][i*9 + d] * senv[lw][x][24 + k3*64 + i*8 + m];
          float val = (ds + dq*RS8) * sev[lw][x*8 + m];
          atomicAdd(&Xacc[cc*72 + tt], val);
        }
      }
    }
  }
}

// K8: h = LN(h+hacc); X = so3_norm(X + Xacc/(attsum+1e-12))
__global__ void k_node_upd(const float* __restrict__ hacc, const float* __restrict__ attsum,
                           const float* __restrict__ Xacc,
                           const float* __restrict__ lg, const float* __restrict__ lb,
                           float* __restrict__ h, float* __restrict__ X){
  int n = blockIdx.x*(blockDim.x >> 6) + (threadIdx.x >> 6);
  int j = threadIdx.x & 63;
  if (n >= N_NODES) return;
  float hv = h[n*LAT + j] + hacc[n*LAT + j];
  float mu = wave_sum(hv) * (1.f/64.f);
  float va = wave_sum(hv*hv) * (1.f/64.f) - mu*mu;
  h[n*LAT + j] = (hv - mu) * rsqrtf(va + 1e-5f) * lg[j] + lb[j];

  float x0, x1 = 0.f;
  float s0 = 0.f, s1 = 0.f, s2 = 0.f;
  { int m = j/9, d = j - m*9;
    x0 = X[n*72 + j] + Xacc[n*72 + j] / (attsum[n*NHEAD + m] + 1e-12f);
    int k3 = irrep_of(d);
    if (k3 == 0) s0 = x0*x0; else if (k3 == 1) s1 = x0*x0; else s2 = x0*x0; }
  if (j < 8){ int tt = 64 + j; int m = tt/9, d = tt - m*9;
    x1 = X[n*72 + tt] + Xacc[n*72 + tt] / (attsum[n*NHEAD + m] + 1e-12f);
    int k3 = irrep_of(d);
    if (k3 == 0) s0 += x1*x1; else if (k3 == 1) s1 += x1*x1; else s2 += x1*x1; }
  s0 = wave_sum(s0); s1 = wave_sum(s1); s2 = wave_sum(s2);
  float sa = rsqrtf(s0*0.125f + 1e-5f), sb = rsqrtf(s1*0.125f + 1e-5f), sc = rsqrtf(s2*0.125f + 1e-5f);
  { int d = j % 9; int k3 = irrep_of(d);
    X[n*72 + j] = x0 * (k3==0 ? sa : (k3==1 ? sb : sc)); }
  if (j < 8){ int d = (64 + j) % 9; int k3 = irrep_of(d);
    X[n*72 + 64 + j] = x1 * (k3==0 ? sa : (k3==1 ? sb : sc)); }
}

// K9: w = h@W_hemb/8 -> (3,8,64); Xo = eq_linear(X,w); node_out
__global__ void k_node_out(const float* __restrict__ h, const float* __restrict__ X,
                           const float* __restrict__ Whemb,
                           float* __restrict__ out){
  __shared__ float sx[4][72];
  int n = blockIdx.x*(blockDim.x >> 6) + (threadIdx.x >> 6);
  int j = threadIdx.x & 63;
  int lw = threadIdx.x >> 6;
  if (n >= N_NODES) return;
  float hv = h[n*LAT + j];
  float wv[24];
  #pragma unroll
  for (int i = 0; i < 24; i++) wv[i] = 0.f;
  #pragma unroll 4
  for (int c = 0; c < LAT; c++){
    float hc = __shfl(hv, c);
    #pragma unroll
    for (int ki = 0; ki < 24; ki++)
      wv[ki] += hc * Whemb[c*1536 + ki*64 + j];
  }
  sx[lw][j] = X[n*72 + j];
  if (j < 8) sx[lw][64 + j] = X[n*72 + 64 + j];
  #pragma unroll
  for (int d = 0; d < 9; d++){
    int k3 = irrep_of(d);
    float acc = 0.f;
    #pragma unroll
    for (int i = 0; i < 8; i++) acc += sx[lw][i*9 + d] * wv[k3*8 + i];
    acc *= 0.125f * RS8;
    int pos;
    if (d == 0)      pos = n*576 + j;
    else if (d < 4)  pos = n*576 + 64  + j*3 + (d - 1);
    else             pos = n*576 + 256 + j*5 + (d - 4);
    out[pos] = acc;
  }
}

// ---- workspace layout (floats) — total 26.56M floats = 106.2 MB ----
static const long O_T    = 0;          // 20.48M  (E*64)
static const long O_ATT  = 20480000;   // 2.56M   (E*8) ; prologue pn/pc/mn/P0 alias here
static const long O_H0   = 23040000;   // 640k
static const long O_H    = 23680000;   // 640k
static const long O_X    = 24320000;   // 720k
static const long O_XACC = 25040000;   // 720k
static const long O_HACC = 25760000;   // 640k
static const long O_AMAX = 26400000;   // 80k
static const long O_ASUM = 26480000;   // 80k

extern "C" void kernel_launch(void* const* d_in, const int* in_sizes, int n_in,
                              void* d_out, int out_size, void* d_ws, size_t ws_size,
                              hipStream_t stream) {
  const float* na    = (const float*)d_in[0];
  const float* phi   = (const float*)d_in[1];
  const float* sph   = (const float*)d_in[2];
  const float* Wn    = (const float*)d_in[4];
  const float* Wc    = (const float*)d_in[5];
  const float* Wcat  = (const float*)d_in[6];
  const float* We    = (const float*)d_in[7];
  const float* ln0g  = (const float*)d_in[8];
  const float* ln0b  = (const float*)d_in[9];
  const float* lneg  = (const float*)d_in[10];
  const float* lneb  = (const float*)d_in[11];
  const float* Wtcat = (const float*)d_in[12];
  const float* Wt0   = (const float*)d_in[13];
  const float* Wh0   = (const float*)d_in[14];
  const float* Wrs   = (const float*)d_in[15];
  const float* Whj   = (const float*)d_in[16];
  const float* lnlg  = (const float*)d_in[17];
  const float* lnlb  = (const float*)d_in[18];
  const float* Wq    = (const float*)d_in[19];
  const float* Wk    = (const float*)d_in[20];
  const float* Whemb = (const float*)d_in[21];
  const float* Wtij  = (const float*)d_in[22];
  const int* ec = (const int*)d_in[23];
  const int* en = (const int*)d_in[24];

  float* ws   = (float*)d_ws;
  float* T    = ws + O_T;
  float* att  = ws + O_ATT;
  float* h0   = ws + O_H0;
  float* h    = ws + O_H;
  float* X    = ws + O_X;
  float* Xacc = ws + O_XACC;
  float* hacc = ws + O_HACC;
  float* amax = ws + O_AMAX;
  float* asum = ws + O_ASUM;
  // prologue-only buffers alias the att region (dead before k_att runs)
  float* pn   = att;
  float* pc   = att + 640000;
  float* mn   = att + 1280000;
  float* P0   = att;               // 1.52M, written after pn/pc/mn are dead

  float* out      = (float*)d_out;
  float* edge_out = out + (long)N_NODES*576;
  // per-layer node precomputes scratch in node_out region (written only at end)
  float* Hk = out;                 // 1.28M
  float* Hw = out + 1280000;       // 2.16M

  hipMemsetAsync(mn,   0, 640000*sizeof(float), stream);
  hipMemsetAsync(Xacc, 0, 720000*sizeof(float), stream);

  k_node_proj<<<(N_NODES*64)/256, 256, 0, stream>>>(na, Wn, Wc, pn, pc);
  k_edge_msg<<<1024, 256, 0, stream>>>(phi, We, ec, en, pn, mn);
  k_node_h<<<N_NODES/4, 256, 0, stream>>>(pc, mn, Wcat, ln0g, ln0b, h0, h);
  k_pre0<<<256, 256, 0, stream>>>(h0, Wtcat, Wh0, P0);
  k_tij<<<1024, 256, 0, stream>>>(P0, phi, sph, Wtcat, lneg, lneb, Wtij, Wt0,
                                  ec, en, T, Xacc, edge_out);
  k_node_X0<<<N_NODES/4, 256, 0, stream>>>(Xacc, X);

  for (int l = 0; l < NL; l++){
    hipMemsetAsync(hacc, 0, 640000*sizeof(float), stream);
    hipMemsetAsync(Xacc, 0, 720000*sizeof(float), stream);
    hipMemsetAsync(asum, 0, 80000*sizeof(float), stream);
    fill_neg_inf<<<(80000 + 255)/256, 256, 0, stream>>>(amax, 80000);

    k_node_mm<128><<<512, 256, 0, stream>>>(h, Wk + l*64*128, 128, 1.f, Hk);
    k_node_mm<216><<<512, 256, 0, stream>>>(h, Whj + (long)l*64*GEN_W, GEN_W, 0.125f, Hw);
    k_att<<<1024, 256, 0, stream>>>(T, Hk, Wq + l*64*128, ec, en, att, amax);
    k_env<<<256, 1024, 0, stream>>>(T, Hw, X, Wrs + (long)l*64*GEN_W, sph,
                                    att, amax, ec, en, hacc, asum, Xacc);
    k_node_upd<<<N_NODES/4, 256, 0, stream>>>(hacc, asum, Xacc, lnlg + l*64, lnlb + l*64, h, X);
  }

  k_node_out<<<N_NODES/4, 256, 0, stream>>>(h, X, Whemb, out);
}